// Round 1
// baseline (2901.447 us; speedup 1.0000x reference)
//
#include <hip/hip_runtime.h>
#include <math.h>

#define NNODES 100000
#define NEDGES 1600000
#define DD 128
#define BN_EPS 1e-5f

// ---------------------------------------------------------------------------
// ws layout (bytes):
//   [0, 51.2MB)      h0  (agg = x + scatter_sum)
//   [51.2, 102.4MB)  h1  (relu(h0@W1+b1))
//   [102.4MB ...)    bnSum[128], bnSq[128], scale[128], shift[128], flag(int)
// h2 goes directly to d_out (f32), then normalized in-place.
// ---------------------------------------------------------------------------

// K1: h0 = x (the (1+eps)*x term, eps=0), zero BN accumulators, detect
// whether edge_index is int32 or int64 (values < 2^31 -> int64 high words 0).
__global__ __launch_bounds__(256) void k_init(const float4* __restrict__ x4,
                                              float4* __restrict__ h0,
                                              float* __restrict__ bnAcc,
                                              const int* __restrict__ e32,
                                              int* __restrict__ flag) {
  long i = (long)blockIdx.x * 256 + threadIdx.x;
  if (i < (long)NNODES * 32) h0[i] = x4[i];
  if (blockIdx.x == 0) {
    bnAcc[threadIdx.x] = 0.f;  // covers bnSum[128] + bnSq[128]
    if (threadIdx.x == 0) {
      int is64 = 1;
      for (int k = 0; k < 64; ++k) is64 &= (e32[2 * k + 1] == 0);
      *flag = is64;
    }
  }
}

// K2: scatter-add. thread t handles edge (t>>5), float4 chunk (t&31).
__global__ __launch_bounds__(256) void k_scatter(const float4* __restrict__ x4,
                                                 const int* __restrict__ e32,
                                                 float* __restrict__ h0,
                                                 const int* __restrict__ flag) {
  long t = (long)blockIdx.x * 256 + threadIdx.x;
  long edge = t >> 5;
  if (edge >= NEDGES) return;
  int c = (int)(t & 31);
  int src, dst;
  if (*flag) {  // int64 layout: little-endian low words at even positions
    src = e32[2 * edge];
    dst = e32[2 * (long)NEDGES + 2 * edge];
  } else {      // int32 layout
    src = e32[edge];
    dst = e32[(long)NEDGES + edge];
  }
  float4 v = x4[(long)src * 32 + c];
  float* o = h0 + (long)dst * DD + c * 4;
  atomicAdd(o + 0, v.x);
  atomicAdd(o + 1, v.y);
  atomicAdd(o + 2, v.z);
  atomicAdd(o + 3, v.w);
}

// K3/K4: C = act(A @ W + bias), A [NNODES,128], W [128,128] row-major.
// Block computes 64 rows x 128 cols. W (64KB) + A-tile (32KB) in LDS.
// Thread (tx=tid&31, ty=tid>>5) computes rows ty*8..+7, cols tx*4..+3.
// BN=true additionally accumulates per-column sum / sumsq into bnSum/bnSq.
template <bool RELU, bool BN>
__global__ __launch_bounds__(256) void k_gemm(const float4* __restrict__ A4,
                                              const float4* __restrict__ W4,
                                              const float4* __restrict__ bias4,
                                              float4* __restrict__ C4,
                                              float* __restrict__ bnSum,
                                              float* __restrict__ bnSq) {
  __shared__ float4 sW[128 * 32];  // 64 KiB: W[k][col/4]
  __shared__ float4 sA[64 * 32];   // 32 KiB: A[row][col/4]
  int tid = threadIdx.x;
  int rowBase = blockIdx.x * 64;

  for (int i = 0; i < 16; ++i) sW[tid + 256 * i] = W4[tid + 256 * i];
  for (int i = 0; i < 8; ++i) {
    int idx = tid + 256 * i;
    int r = rowBase + (idx >> 5);
    float4 v = {0.f, 0.f, 0.f, 0.f};
    if (r < NNODES) v = A4[(long)r * 32 + (idx & 31)];
    sA[idx] = v;
  }
  __syncthreads();

  int tx = tid & 31;
  int ty = tid >> 5;
  float acc[8][4];
#pragma unroll
  for (int i = 0; i < 8; ++i)
#pragma unroll
    for (int j = 0; j < 4; ++j) acc[i][j] = 0.f;

  for (int kk = 0; kk < 32; ++kk) {  // k = 4*kk
    float4 w0 = sW[(4 * kk + 0) * 32 + tx];
    float4 w1 = sW[(4 * kk + 1) * 32 + tx];
    float4 w2 = sW[(4 * kk + 2) * 32 + tx];
    float4 w3 = sW[(4 * kk + 3) * 32 + tx];
#pragma unroll
    for (int i = 0; i < 8; ++i) {
      float4 a = sA[(ty * 8 + i) * 32 + kk];
      acc[i][0] = fmaf(a.x, w0.x, fmaf(a.y, w1.x, fmaf(a.z, w2.x, fmaf(a.w, w3.x, acc[i][0]))));
      acc[i][1] = fmaf(a.x, w0.y, fmaf(a.y, w1.y, fmaf(a.z, w2.y, fmaf(a.w, w3.y, acc[i][1]))));
      acc[i][2] = fmaf(a.x, w0.z, fmaf(a.y, w1.z, fmaf(a.z, w2.z, fmaf(a.w, w3.z, acc[i][2]))));
      acc[i][3] = fmaf(a.x, w0.w, fmaf(a.y, w1.w, fmaf(a.z, w2.w, fmaf(a.w, w3.w, acc[i][3]))));
    }
  }

  float4 b = bias4[tx];
  float ls[4] = {0.f, 0.f, 0.f, 0.f};
  float lq[4] = {0.f, 0.f, 0.f, 0.f};
#pragma unroll
  for (int i = 0; i < 8; ++i) {
    int r = rowBase + ty * 8 + i;
    if (r < NNODES) {
      float4 v;
      v.x = acc[i][0] + b.x;
      v.y = acc[i][1] + b.y;
      v.z = acc[i][2] + b.z;
      v.w = acc[i][3] + b.w;
      if (RELU) {
        v.x = fmaxf(v.x, 0.f);
        v.y = fmaxf(v.y, 0.f);
        v.z = fmaxf(v.z, 0.f);
        v.w = fmaxf(v.w, 0.f);
      }
      C4[(long)r * 32 + tx] = v;
      if (BN) {
        ls[0] += v.x; lq[0] += v.x * v.x;
        ls[1] += v.y; lq[1] += v.y * v.y;
        ls[2] += v.z; lq[2] += v.z * v.z;
        ls[3] += v.w; lq[3] += v.w * v.w;
      }
    }
  }

  if (BN) {
    __syncthreads();
    float* s1 = (float*)sA;        // [8][128] partial sums
    float* s2 = s1 + 8 * 128;      // [8][128] partial sumsq
#pragma unroll
    for (int j = 0; j < 4; ++j) {
      s1[ty * 128 + tx * 4 + j] = ls[j];
      s2[ty * 128 + tx * 4 + j] = lq[j];
    }
    __syncthreads();
    if (tid < 128) {
      float t1 = 0.f, t2 = 0.f;
      for (int g = 0; g < 8; ++g) {
        t1 += s1[g * 128 + tid];
        t2 += s2[g * 128 + tid];
      }
      atomicAdd(bnSum + tid, t1);
      atomicAdd(bnSq + tid, t2);
    }
  }
}

// K5: finalize BN -> per-column scale/shift.
__global__ void k_bnfin(const float* __restrict__ bnSum, const float* __restrict__ bnSq,
                        const float* __restrict__ gamma, const float* __restrict__ beta,
                        float* __restrict__ scale, float* __restrict__ shift) {
  int c = threadIdx.x;
  float m = bnSum[c] * (1.0f / NNODES);
  float var = bnSq[c] * (1.0f / NNODES) - m * m;  // biased variance
  float sc = gamma[c] * rsqrtf(var + BN_EPS);
  scale[c] = sc;
  shift[c] = beta[c] - m * sc;
}

// K6: out = h2*scale + shift + x (in-place on d_out).
__global__ __launch_bounds__(256) void k_epi(const float4* __restrict__ h2,
                                             const float4* __restrict__ x4,
                                             const float4* __restrict__ scale4,
                                             const float4* __restrict__ shift4,
                                             float4* __restrict__ out4) {
  long i = (long)blockIdx.x * 256 + threadIdx.x;
  if (i >= (long)NNODES * 32) return;
  int c = (int)(i & 31);
  float4 h = h2[i], xx = x4[i], sc = scale4[c], sh = shift4[c];
  float4 o;
  o.x = fmaf(h.x, sc.x, sh.x) + xx.x;
  o.y = fmaf(h.y, sc.y, sh.y) + xx.y;
  o.z = fmaf(h.z, sc.z, sh.z) + xx.z;
  o.w = fmaf(h.w, sc.w, sh.w) + xx.w;
  out4[i] = o;
}

extern "C" void kernel_launch(void* const* d_in, const int* in_sizes, int n_in,
                              void* d_out, int out_size, void* d_ws, size_t ws_size,
                              hipStream_t stream) {
  const float* x     = (const float*)d_in[0];
  const int*   e32   = (const int*)d_in[1];
  const float* W1    = (const float*)d_in[2];
  const float* b1    = (const float*)d_in[3];
  const float* W2    = (const float*)d_in[4];
  const float* b2    = (const float*)d_in[5];
  const float* gamma = (const float*)d_in[6];
  const float* beta  = (const float*)d_in[7];
  float* out = (float*)d_out;

  char* ws = (char*)d_ws;
  size_t NB = (size_t)NNODES * DD * sizeof(float);  // 51.2 MB
  float* h0    = (float*)ws;
  float* h1    = (float*)(ws + NB);
  float* bnSum = (float*)(ws + 2 * NB);
  float* bnSq  = bnSum + 128;
  float* scale = bnSum + 256;
  float* shift = bnSum + 384;
  int*   flag  = (int*)(bnSum + 512);

  // 100000*32 float4 = 3.2M threads = 12500 blocks exactly
  k_init<<<12500, 256, 0, stream>>>((const float4*)x, (float4*)h0, bnSum, e32, flag);
  // 1.6M edges * 32 chunks = 51.2M threads = 200000 blocks exactly
  k_scatter<<<200000, 256, 0, stream>>>((const float4*)x, e32, h0, flag);
  // ceil(100000/64) = 1563 blocks
  k_gemm<true, false><<<1563, 256, 0, stream>>>(
      (const float4*)h0, (const float4*)W1, (const float4*)b1, (float4*)h1,
      nullptr, nullptr);
  k_gemm<false, true><<<1563, 256, 0, stream>>>(
      (const float4*)h1, (const float4*)W2, (const float4*)b2, (float4*)out,
      bnSum, bnSq);
  k_bnfin<<<1, 128, 0, stream>>>(bnSum, bnSq, gamma, beta, scale, shift);
  k_epi<<<12500, 256, 0, stream>>>((const float4*)out, (const float4*)x,
                                   (const float4*)scale, (const float4*)shift,
                                   (float4*)out);
}

// Round 2
// 737.676 us; speedup vs baseline: 3.9332x; 3.9332x over previous
//
#include <hip/hip_runtime.h>
#include <math.h>

#define NNODES 100000
#define NEDGES 1600000
#define DD 128
#define BN_EPS 1e-5f

// ---------------------------------------------------------------------------
// ws layout (bytes):
//   [0, NB)        h0  (agg = x + gather_sum)                 NB = 51.2 MB
//   [NB, 2NB)      h1  (relu(h0@W1+b1))  -- ALSO aliased (before GEMM1) by:
//                     deg[100000] | rowPtr[100001] | cursor[100000] |
//                     edgeSrc[1600000]   (7.6 MB total, dead after k_gather)
//   [2NB, ...)     bnSum[128], bnSq[128], scale[128], shift[128], flag(int)
// ---------------------------------------------------------------------------

// K1: zero deg + BN accumulators; detect int32 vs int64 edge_index layout
// (values < 2^31 and nonneg -> int64 high words are all zero).
__global__ __launch_bounds__(256) void k_init(int* __restrict__ deg,
                                              float* __restrict__ bnAcc,
                                              const int* __restrict__ e32,
                                              int* __restrict__ flag) {
  int i = blockIdx.x * 256 + threadIdx.x;
  if (i < NNODES) deg[i] = 0;
  if (blockIdx.x == 0) {
    bnAcc[threadIdx.x] = 0.f;  // covers bnSum[128] + bnSq[128]
    if (threadIdx.x == 0) {
      int is64 = 1;
      for (int k = 0; k < 64; ++k) is64 &= (e32[2 * k + 1] == 0);
      *flag = is64;
    }
  }
}

// K2: histogram of dst.
__global__ __launch_bounds__(256) void k_count(const int* __restrict__ e32,
                                               int* __restrict__ deg,
                                               const int* __restrict__ flag) {
  int i = blockIdx.x * 256 + threadIdx.x;
  if (i >= NEDGES) return;
  int dst = (*flag) ? e32[2 * (long)NEDGES + 2 * (long)i]
                    : e32[(long)NEDGES + i];
  atomicAdd(&deg[dst], 1);
}

// K3: exclusive scan of deg -> rowPtr (and cursor copy). One block, 1024 thr.
__global__ __launch_bounds__(1024) void k_scan(const int* __restrict__ deg,
                                               int* __restrict__ rowPtr,
                                               int* __restrict__ cursor) {
  __shared__ int s[1024];
  int tid = threadIdx.x;
  const int CH = 98;  // 1024*98 >= 100000
  int b = tid * CH;
  int e = b + CH; if (e > NNODES) e = NNODES;
  int sum = 0;
  for (int i = b; i < e; ++i) sum += deg[i];
  s[tid] = sum;
  __syncthreads();
  for (int off = 1; off < 1024; off <<= 1) {
    int v = (tid >= off) ? s[tid - off] : 0;
    __syncthreads();
    s[tid] += v;
    __syncthreads();
  }
  int excl = (tid == 0) ? 0 : s[tid - 1];
  for (int i = b; i < e; ++i) {
    rowPtr[i] = excl;
    cursor[i] = excl;
    excl += deg[i];
  }
  if (tid == 1023) rowPtr[NNODES] = s[1023];
}

// K4: scatter src indices into CSR slots.
__global__ __launch_bounds__(256) void k_fill(const int* __restrict__ e32,
                                              int* __restrict__ cursor,
                                              int* __restrict__ edgeSrc,
                                              const int* __restrict__ flag) {
  int i = blockIdx.x * 256 + threadIdx.x;
  if (i >= NEDGES) return;
  int src, dst;
  if (*flag) {
    src = e32[2 * (long)i];
    dst = e32[2 * (long)NEDGES + 2 * (long)i];
  } else {
    src = e32[i];
    dst = e32[(long)NEDGES + i];
  }
  int pos = atomicAdd(&cursor[dst], 1);
  edgeSrc[pos] = src;
}

// K5: gather-accumulate. One 64-lane wave per node; lane owns float2 (8B).
__global__ __launch_bounds__(256) void k_gather(const float2* __restrict__ x2,
                                                const int* __restrict__ rowPtr,
                                                const int* __restrict__ edgeSrc,
                                                float2* __restrict__ h0) {
  int wave = (blockIdx.x * 256 + threadIdx.x) >> 6;
  int lane = threadIdx.x & 63;
  if (wave >= NNODES) return;
  long base = (long)wave * 64 + lane;
  int beg = rowPtr[wave], end = rowPtr[wave + 1];
  float2 acc = x2[base];
  int e = beg;
  for (; e + 4 <= end; e += 4) {
    int s0 = edgeSrc[e + 0], s1 = edgeSrc[e + 1];
    int s2 = edgeSrc[e + 2], s3 = edgeSrc[e + 3];
    float2 v0 = x2[(long)s0 * 64 + lane];
    float2 v1 = x2[(long)s1 * 64 + lane];
    float2 v2 = x2[(long)s2 * 64 + lane];
    float2 v3 = x2[(long)s3 * 64 + lane];
    acc.x += v0.x + v1.x + v2.x + v3.x;
    acc.y += v0.y + v1.y + v2.y + v3.y;
  }
  for (; e < end; ++e) {
    int s = edgeSrc[e];
    float2 v = x2[(long)s * 64 + lane];
    acc.x += v.x;
    acc.y += v.y;
  }
  h0[base] = acc;
}

// K6/K7: C = act(A @ W + bias), A [NNODES,128], W [128,128] row-major.
// Block computes 64 rows x 128 cols. W (64KB) + A-tile (32KB) in LDS.
template <bool RELU, bool BN>
__global__ __launch_bounds__(256) void k_gemm(const float4* __restrict__ A4,
                                              const float4* __restrict__ W4,
                                              const float4* __restrict__ bias4,
                                              float4* __restrict__ C4,
                                              float* __restrict__ bnSum,
                                              float* __restrict__ bnSq) {
  __shared__ float4 sW[128 * 32];  // 64 KiB: W[k][col/4]
  __shared__ float4 sA[64 * 32];   // 32 KiB: A[row][col/4]
  int tid = threadIdx.x;
  int rowBase = blockIdx.x * 64;

  for (int i = 0; i < 16; ++i) sW[tid + 256 * i] = W4[tid + 256 * i];
  for (int i = 0; i < 8; ++i) {
    int idx = tid + 256 * i;
    int r = rowBase + (idx >> 5);
    float4 v = {0.f, 0.f, 0.f, 0.f};
    if (r < NNODES) v = A4[(long)r * 32 + (idx & 31)];
    sA[idx] = v;
  }
  __syncthreads();

  int tx = tid & 31;
  int ty = tid >> 5;
  float acc[8][4];
#pragma unroll
  for (int i = 0; i < 8; ++i)
#pragma unroll
    for (int j = 0; j < 4; ++j) acc[i][j] = 0.f;

  for (int kk = 0; kk < 32; ++kk) {
    float4 w0 = sW[(4 * kk + 0) * 32 + tx];
    float4 w1 = sW[(4 * kk + 1) * 32 + tx];
    float4 w2 = sW[(4 * kk + 2) * 32 + tx];
    float4 w3 = sW[(4 * kk + 3) * 32 + tx];
#pragma unroll
    for (int i = 0; i < 8; ++i) {
      float4 a = sA[(ty * 8 + i) * 32 + kk];
      acc[i][0] = fmaf(a.x, w0.x, fmaf(a.y, w1.x, fmaf(a.z, w2.x, fmaf(a.w, w3.x, acc[i][0]))));
      acc[i][1] = fmaf(a.x, w0.y, fmaf(a.y, w1.y, fmaf(a.z, w2.y, fmaf(a.w, w3.y, acc[i][1]))));
      acc[i][2] = fmaf(a.x, w0.z, fmaf(a.y, w1.z, fmaf(a.z, w2.z, fmaf(a.w, w3.z, acc[i][2]))));
      acc[i][3] = fmaf(a.x, w0.w, fmaf(a.y, w1.w, fmaf(a.z, w2.w, fmaf(a.w, w3.w, acc[i][3]))));
    }
  }

  float4 b = bias4[tx];
  float ls[4] = {0.f, 0.f, 0.f, 0.f};
  float lq[4] = {0.f, 0.f, 0.f, 0.f};
#pragma unroll
  for (int i = 0; i < 8; ++i) {
    int r = rowBase + ty * 8 + i;
    if (r < NNODES) {
      float4 v;
      v.x = acc[i][0] + b.x;
      v.y = acc[i][1] + b.y;
      v.z = acc[i][2] + b.z;
      v.w = acc[i][3] + b.w;
      if (RELU) {
        v.x = fmaxf(v.x, 0.f);
        v.y = fmaxf(v.y, 0.f);
        v.z = fmaxf(v.z, 0.f);
        v.w = fmaxf(v.w, 0.f);
      }
      C4[(long)r * 32 + tx] = v;
      if (BN) {
        ls[0] += v.x; lq[0] += v.x * v.x;
        ls[1] += v.y; lq[1] += v.y * v.y;
        ls[2] += v.z; lq[2] += v.z * v.z;
        ls[3] += v.w; lq[3] += v.w * v.w;
      }
    }
  }

  if (BN) {
    __syncthreads();
    float* s1 = (float*)sA;        // [8][128] partial sums
    float* s2 = s1 + 8 * 128;      // [8][128] partial sumsq
#pragma unroll
    for (int j = 0; j < 4; ++j) {
      s1[ty * 128 + tx * 4 + j] = ls[j];
      s2[ty * 128 + tx * 4 + j] = lq[j];
    }
    __syncthreads();
    if (tid < 128) {
      float t1 = 0.f, t2 = 0.f;
      for (int g = 0; g < 8; ++g) {
        t1 += s1[g * 128 + tid];
        t2 += s2[g * 128 + tid];
      }
      atomicAdd(bnSum + tid, t1);
      atomicAdd(bnSq + tid, t2);
    }
  }
}

// K8: finalize BN -> per-column scale/shift.
__global__ void k_bnfin(const float* __restrict__ bnSum, const float* __restrict__ bnSq,
                        const float* __restrict__ gamma, const float* __restrict__ beta,
                        float* __restrict__ scale, float* __restrict__ shift) {
  int c = threadIdx.x;
  float m = bnSum[c] * (1.0f / NNODES);
  float var = bnSq[c] * (1.0f / NNODES) - m * m;  // biased variance
  float sc = gamma[c] * rsqrtf(var + BN_EPS);
  scale[c] = sc;
  shift[c] = beta[c] - m * sc;
}

// K9: out = h2*scale + shift + x (in-place on d_out).
__global__ __launch_bounds__(256) void k_epi(const float4* __restrict__ h2,
                                             const float4* __restrict__ x4,
                                             const float4* __restrict__ scale4,
                                             const float4* __restrict__ shift4,
                                             float4* __restrict__ out4) {
  long i = (long)blockIdx.x * 256 + threadIdx.x;
  if (i >= (long)NNODES * 32) return;
  int c = (int)(i & 31);
  float4 h = h2[i], xx = x4[i], sc = scale4[c], sh = shift4[c];
  float4 o;
  o.x = fmaf(h.x, sc.x, sh.x) + xx.x;
  o.y = fmaf(h.y, sc.y, sh.y) + xx.y;
  o.z = fmaf(h.z, sc.z, sh.z) + xx.z;
  o.w = fmaf(h.w, sc.w, sh.w) + xx.w;
  out4[i] = o;
}

extern "C" void kernel_launch(void* const* d_in, const int* in_sizes, int n_in,
                              void* d_out, int out_size, void* d_ws, size_t ws_size,
                              hipStream_t stream) {
  const float* x     = (const float*)d_in[0];
  const int*   e32   = (const int*)d_in[1];
  const float* W1    = (const float*)d_in[2];
  const float* b1    = (const float*)d_in[3];
  const float* W2    = (const float*)d_in[4];
  const float* b2    = (const float*)d_in[5];
  const float* gamma = (const float*)d_in[6];
  const float* beta  = (const float*)d_in[7];
  float* out = (float*)d_out;

  char* ws = (char*)d_ws;
  size_t NB = (size_t)NNODES * DD * sizeof(float);  // 51.2 MB
  float* h0 = (float*)ws;
  float* h1 = (float*)(ws + NB);

  // CSR scratch aliases h1's region (dead before GEMM1 writes h1).
  int* deg     = (int*)(ws + NB);
  int* rowPtr  = deg + NNODES;
  int* cursor  = rowPtr + NNODES + 1;
  int* edgeSrc = cursor + NNODES;

  float* bnSum = (float*)(ws + 2 * NB);
  float* bnSq  = bnSum + 128;
  float* scale = bnSum + 256;
  float* shift = bnSum + 384;
  int*   flag  = (int*)(bnSum + 512);

  k_init<<<(NNODES + 255) / 256, 256, 0, stream>>>(deg, bnSum, e32, flag);
  k_count<<<(NEDGES + 255) / 256, 256, 0, stream>>>(e32, deg, flag);
  k_scan<<<1, 1024, 0, stream>>>(deg, rowPtr, cursor);
  k_fill<<<(NEDGES + 255) / 256, 256, 0, stream>>>(e32, cursor, edgeSrc, flag);
  // one wave per node: 100000 waves = 25000 blocks of 256 (4 waves)
  k_gather<<<25000, 256, 0, stream>>>((const float2*)x, rowPtr, edgeSrc,
                                      (float2*)h0);
  k_gemm<true, false><<<1563, 256, 0, stream>>>(
      (const float4*)h0, (const float4*)W1, (const float4*)b1, (float4*)h1,
      nullptr, nullptr);
  k_gemm<false, true><<<1563, 256, 0, stream>>>(
      (const float4*)h1, (const float4*)W2, (const float4*)b2, (float4*)out,
      bnSum, bnSq);
  k_bnfin<<<1, 128, 0, stream>>>(bnSum, bnSq, gamma, beta, scale, shift);
  k_epi<<<12500, 256, 0, stream>>>((const float4*)out, (const float4*)x,
                                   (const float4*)scale, (const float4*)shift,
                                   (float4*)out);
}

// Round 3
// 521.243 us; speedup vs baseline: 5.5664x; 1.4152x over previous
//
#include <hip/hip_runtime.h>
#include <math.h>

#define NNODES 100000
#define NEDGES 1600000
#define DD 128
#define BN_EPS 1e-5f

// ---------------------------------------------------------------------------
// ws layout (bytes):
//   [0, NB)        h0  (agg = x + gather_sum)                 NB = 51.2 MB
//   [NB, 2NB)      h1  (relu(h0@W1+b1))  -- ALSO aliased (before GEMM1) by:
//       deg[100000] | rowPtr[100004 pad] | cursor[100000] | edgeSrc[1600000]
//       | blockSums[128] | blockOff[128]   (~7.6 MB, dead after k_gather)
//   [2NB, ...)     bnSum[128], bnSq[128], scale[128], shift[128], flag(int)
// ---------------------------------------------------------------------------

#define SCAN_BLOCKS 98  // ceil(100000 / 1024)

// K1: zero deg + BN accumulators; detect int32 vs int64 edge_index layout
// (values < 2^31 and nonneg -> int64 high words are all zero).
__global__ __launch_bounds__(256) void k_init(int* __restrict__ deg,
                                              float* __restrict__ bnAcc,
                                              const int* __restrict__ e32,
                                              int* __restrict__ flag) {
  int i = blockIdx.x * 256 + threadIdx.x;
  if (i < NNODES) deg[i] = 0;
  if (blockIdx.x == 0) {
    bnAcc[threadIdx.x] = 0.f;  // covers bnSum[128] + bnSq[128]
    if (threadIdx.x == 0) {
      int is64 = 1;
      for (int k = 0; k < 64; ++k) is64 &= (e32[2 * k + 1] == 0);
      *flag = is64;
    }
  }
}

// K2: histogram of dst.
__global__ __launch_bounds__(256) void k_count(const int* __restrict__ e32,
                                               int* __restrict__ deg,
                                               const int* __restrict__ flag) {
  int i = blockIdx.x * 256 + threadIdx.x;
  if (i >= NEDGES) return;
  int dst = (*flag) ? e32[2 * (long)NEDGES + 2 * (long)i]
                    : e32[(long)NEDGES + i];
  atomicAdd(&deg[dst], 1);
}

// K3a: per-block (1024-element) reduction of deg -> blockSums.
__global__ __launch_bounds__(256) void k_scanA(const int4* __restrict__ deg4,
                                               int* __restrict__ blockSums) {
  __shared__ int s[256];
  int tid = threadIdx.x;
  int idx = blockIdx.x * 256 + tid;
  int4 d = {0, 0, 0, 0};
  if (idx < NNODES / 4) d = deg4[idx];
  s[tid] = d.x + d.y + d.z + d.w;
  __syncthreads();
  for (int off = 128; off > 0; off >>= 1) {
    if (tid < off) s[tid] += s[tid + off];
    __syncthreads();
  }
  if (tid == 0) blockSums[blockIdx.x] = s[0];
}

// K3b: exclusive scan of the 98 block sums (one tiny block).
__global__ __launch_bounds__(128) void k_scanB(const int* __restrict__ blockSums,
                                               int* __restrict__ blockOff,
                                               int* __restrict__ rowPtr) {
  __shared__ int s[128];
  int tid = threadIdx.x;
  s[tid] = (tid < SCAN_BLOCKS) ? blockSums[tid] : 0;
  __syncthreads();
  for (int off = 1; off < 128; off <<= 1) {
    int v = (tid >= off) ? s[tid - off] : 0;
    __syncthreads();
    s[tid] += v;
    __syncthreads();
  }
  if (tid < SCAN_BLOCKS) blockOff[tid] = (tid == 0) ? 0 : s[tid - 1];
  if (tid == 0) rowPtr[NNODES] = NEDGES;  // total degree is known
}

// K3c: local exclusive scan (1024 elems/block) + blockOff -> rowPtr, cursor.
__global__ __launch_bounds__(256) void k_scanC(const int4* __restrict__ deg4,
                                               const int* __restrict__ blockOff,
                                               int4* __restrict__ rowPtr4,
                                               int4* __restrict__ cursor4) {
  __shared__ int s[256];
  int tid = threadIdx.x;
  int idx = blockIdx.x * 256 + tid;
  int4 d = {0, 0, 0, 0};
  if (idx < NNODES / 4) d = deg4[idx];
  s[tid] = d.x + d.y + d.z + d.w;
  __syncthreads();
  for (int off = 1; off < 256; off <<= 1) {
    int v = (tid >= off) ? s[tid - off] : 0;
    __syncthreads();
    s[tid] += v;
    __syncthreads();
  }
  if (idx < NNODES / 4) {
    int excl = blockOff[blockIdx.x] + ((tid == 0) ? 0 : s[tid - 1]);
    int4 r;
    r.x = excl;
    r.y = r.x + d.x;
    r.z = r.y + d.y;
    r.w = r.z + d.z;
    rowPtr4[idx] = r;
    cursor4[idx] = r;
  }
}

// K4: scatter src indices into CSR slots.
__global__ __launch_bounds__(256) void k_fill(const int* __restrict__ e32,
                                              int* __restrict__ cursor,
                                              int* __restrict__ edgeSrc,
                                              const int* __restrict__ flag) {
  int i = blockIdx.x * 256 + threadIdx.x;
  if (i >= NEDGES) return;
  int src, dst;
  if (*flag) {
    src = e32[2 * (long)i];
    dst = e32[2 * (long)NEDGES + 2 * (long)i];
  } else {
    src = e32[i];
    dst = e32[(long)NEDGES + i];
  }
  int pos = atomicAdd(&cursor[dst], 1);
  edgeSrc[pos] = src;
}

// K5: gather-accumulate. One 64-lane wave per node; lane owns float2 (8B).
__global__ __launch_bounds__(256) void k_gather(const float2* __restrict__ x2,
                                                const int* __restrict__ rowPtr,
                                                const int* __restrict__ edgeSrc,
                                                float2* __restrict__ h0) {
  int wave = (blockIdx.x * 256 + threadIdx.x) >> 6;
  int lane = threadIdx.x & 63;
  if (wave >= NNODES) return;
  long base = (long)wave * 64 + lane;
  int beg = rowPtr[wave], end = rowPtr[wave + 1];
  float2 acc = x2[base];
  int e = beg;
  for (; e + 4 <= end; e += 4) {
    int s0 = edgeSrc[e + 0], s1 = edgeSrc[e + 1];
    int s2 = edgeSrc[e + 2], s3 = edgeSrc[e + 3];
    float2 v0 = x2[(long)s0 * 64 + lane];
    float2 v1 = x2[(long)s1 * 64 + lane];
    float2 v2 = x2[(long)s2 * 64 + lane];
    float2 v3 = x2[(long)s3 * 64 + lane];
    acc.x += v0.x + v1.x + v2.x + v3.x;
    acc.y += v0.y + v1.y + v2.y + v3.y;
  }
  for (; e < end; ++e) {
    int s = edgeSrc[e];
    float2 v = x2[(long)s * 64 + lane];
    acc.x += v.x;
    acc.y += v.y;
  }
  h0[base] = acc;
}

// K6/K7: C = act(A @ W + bias), A [NNODES,128], W [128,128] row-major.
// Block computes 64 rows x 128 cols. W (64KB) + A-tile (32KB) in LDS.
template <bool RELU, bool BN>
__global__ __launch_bounds__(256) void k_gemm(const float4* __restrict__ A4,
                                              const float4* __restrict__ W4,
                                              const float4* __restrict__ bias4,
                                              float4* __restrict__ C4,
                                              float* __restrict__ bnSum,
                                              float* __restrict__ bnSq) {
  __shared__ float4 sW[128 * 32];  // 64 KiB: W[k][col/4]
  __shared__ float4 sA[64 * 32];   // 32 KiB: A[row][col/4]
  int tid = threadIdx.x;
  int rowBase = blockIdx.x * 64;

  for (int i = 0; i < 16; ++i) sW[tid + 256 * i] = W4[tid + 256 * i];
  for (int i = 0; i < 8; ++i) {
    int idx = tid + 256 * i;
    int r = rowBase + (idx >> 5);
    float4 v = {0.f, 0.f, 0.f, 0.f};
    if (r < NNODES) v = A4[(long)r * 32 + (idx & 31)];
    sA[idx] = v;
  }
  __syncthreads();

  int tx = tid & 31;
  int ty = tid >> 5;
  float acc[8][4];
#pragma unroll
  for (int i = 0; i < 8; ++i)
#pragma unroll
    for (int j = 0; j < 4; ++j) acc[i][j] = 0.f;

  for (int kk = 0; kk < 32; ++kk) {
    float4 w0 = sW[(4 * kk + 0) * 32 + tx];
    float4 w1 = sW[(4 * kk + 1) * 32 + tx];
    float4 w2 = sW[(4 * kk + 2) * 32 + tx];
    float4 w3 = sW[(4 * kk + 3) * 32 + tx];
#pragma unroll
    for (int i = 0; i < 8; ++i) {
      float4 a = sA[(ty * 8 + i) * 32 + kk];
      acc[i][0] = fmaf(a.x, w0.x, fmaf(a.y, w1.x, fmaf(a.z, w2.x, fmaf(a.w, w3.x, acc[i][0]))));
      acc[i][1] = fmaf(a.x, w0.y, fmaf(a.y, w1.y, fmaf(a.z, w2.y, fmaf(a.w, w3.y, acc[i][1]))));
      acc[i][2] = fmaf(a.x, w0.z, fmaf(a.y, w1.z, fmaf(a.z, w2.z, fmaf(a.w, w3.z, acc[i][2]))));
      acc[i][3] = fmaf(a.x, w0.w, fmaf(a.y, w1.w, fmaf(a.z, w2.w, fmaf(a.w, w3.w, acc[i][3]))));
    }
  }

  float4 b = bias4[tx];
  float ls[4] = {0.f, 0.f, 0.f, 0.f};
  float lq[4] = {0.f, 0.f, 0.f, 0.f};
#pragma unroll
  for (int i = 0; i < 8; ++i) {
    int r = rowBase + ty * 8 + i;
    if (r < NNODES) {
      float4 v;
      v.x = acc[i][0] + b.x;
      v.y = acc[i][1] + b.y;
      v.z = acc[i][2] + b.z;
      v.w = acc[i][3] + b.w;
      if (RELU) {
        v.x = fmaxf(v.x, 0.f);
        v.y = fmaxf(v.y, 0.f);
        v.z = fmaxf(v.z, 0.f);
        v.w = fmaxf(v.w, 0.f);
      }
      C4[(long)r * 32 + tx] = v;
      if (BN) {
        ls[0] += v.x; lq[0] += v.x * v.x;
        ls[1] += v.y; lq[1] += v.y * v.y;
        ls[2] += v.z; lq[2] += v.z * v.z;
        ls[3] += v.w; lq[3] += v.w * v.w;
      }
    }
  }

  if (BN) {
    __syncthreads();
    float* s1 = (float*)sA;        // [8][128] partial sums
    float* s2 = s1 + 8 * 128;      // [8][128] partial sumsq
#pragma unroll
    for (int j = 0; j < 4; ++j) {
      s1[ty * 128 + tx * 4 + j] = ls[j];
      s2[ty * 128 + tx * 4 + j] = lq[j];
    }
    __syncthreads();
    if (tid < 128) {
      float t1 = 0.f, t2 = 0.f;
      for (int g = 0; g < 8; ++g) {
        t1 += s1[g * 128 + tid];
        t2 += s2[g * 128 + tid];
      }
      atomicAdd(bnSum + tid, t1);
      atomicAdd(bnSq + tid, t2);
    }
  }
}

// K8: finalize BN -> per-column scale/shift.
__global__ void k_bnfin(const float* __restrict__ bnSum, const float* __restrict__ bnSq,
                        const float* __restrict__ gamma, const float* __restrict__ beta,
                        float* __restrict__ scale, float* __restrict__ shift) {
  int c = threadIdx.x;
  float m = bnSum[c] * (1.0f / NNODES);
  float var = bnSq[c] * (1.0f / NNODES) - m * m;  // biased variance
  float sc = gamma[c] * rsqrtf(var + BN_EPS);
  scale[c] = sc;
  shift[c] = beta[c] - m * sc;
}

// K9: out = h2*scale + shift + x (in-place on d_out).
__global__ __launch_bounds__(256) void k_epi(const float4* __restrict__ h2,
                                             const float4* __restrict__ x4,
                                             const float4* __restrict__ scale4,
                                             const float4* __restrict__ shift4,
                                             float4* __restrict__ out4) {
  long i = (long)blockIdx.x * 256 + threadIdx.x;
  if (i >= (long)NNODES * 32) return;
  int c = (int)(i & 31);
  float4 h = h2[i], xx = x4[i], sc = scale4[c], sh = shift4[c];
  float4 o;
  o.x = fmaf(h.x, sc.x, sh.x) + xx.x;
  o.y = fmaf(h.y, sc.y, sh.y) + xx.y;
  o.z = fmaf(h.z, sc.z, sh.z) + xx.z;
  o.w = fmaf(h.w, sc.w, sh.w) + xx.w;
  out4[i] = o;
}

extern "C" void kernel_launch(void* const* d_in, const int* in_sizes, int n_in,
                              void* d_out, int out_size, void* d_ws, size_t ws_size,
                              hipStream_t stream) {
  const float* x     = (const float*)d_in[0];
  const int*   e32   = (const int*)d_in[1];
  const float* W1    = (const float*)d_in[2];
  const float* b1    = (const float*)d_in[3];
  const float* W2    = (const float*)d_in[4];
  const float* b2    = (const float*)d_in[5];
  const float* gamma = (const float*)d_in[6];
  const float* beta  = (const float*)d_in[7];
  float* out = (float*)d_out;

  char* ws = (char*)d_ws;
  size_t NB = (size_t)NNODES * DD * sizeof(float);  // 51.2 MB
  float* h0 = (float*)ws;
  float* h1 = (float*)(ws + NB);

  // CSR scratch aliases h1's region (dead before GEMM1 writes h1).
  // All arrays 16B-aligned: deg@0, rowPtr@400000, cursor@800016, ...
  int* deg       = (int*)(ws + NB);
  int* rowPtr    = deg + NNODES;            // [NNODES+4] padded
  int* cursor    = rowPtr + NNODES + 4;     // [NNODES]
  int* edgeSrc   = cursor + NNODES;         // [NEDGES]
  int* blockSums = edgeSrc + NEDGES;        // [128]
  int* blockOff  = blockSums + 128;         // [128]

  float* bnSum = (float*)(ws + 2 * NB);
  float* bnSq  = bnSum + 128;
  float* scale = bnSum + 256;
  float* shift = bnSum + 384;
  int*   flag  = (int*)(bnSum + 512);

  k_init<<<(NNODES + 255) / 256, 256, 0, stream>>>(deg, bnSum, e32, flag);
  k_count<<<(NEDGES + 255) / 256, 256, 0, stream>>>(e32, deg, flag);
  k_scanA<<<SCAN_BLOCKS, 256, 0, stream>>>((const int4*)deg, blockSums);
  k_scanB<<<1, 128, 0, stream>>>(blockSums, blockOff, rowPtr);
  k_scanC<<<SCAN_BLOCKS, 256, 0, stream>>>((const int4*)deg, blockOff,
                                           (int4*)rowPtr, (int4*)cursor);
  k_fill<<<(NEDGES + 255) / 256, 256, 0, stream>>>(e32, cursor, edgeSrc, flag);
  // one wave per node: 100000 waves = 25000 blocks of 256 (4 waves)
  k_gather<<<25000, 256, 0, stream>>>((const float2*)x, rowPtr, edgeSrc,
                                      (float2*)h0);
  k_gemm<true, false><<<1563, 256, 0, stream>>>(
      (const float4*)h0, (const float4*)W1, (const float4*)b1, (float4*)h1,
      nullptr, nullptr);
  k_gemm<false, true><<<1563, 256, 0, stream>>>(
      (const float4*)h1, (const float4*)W2, (const float4*)b2, (float4*)out,
      bnSum, bnSq);
  k_bnfin<<<1, 128, 0, stream>>>(bnSum, bnSq, gamma, beta, scale, shift);
  k_epi<<<12500, 256, 0, stream>>>((const float4*)out, (const float4*)x,
                                   (const float4*)scale, (const float4*)shift,
                                   (float4*)out);
}

// Round 4
// 347.194 us; speedup vs baseline: 8.3569x; 1.5013x over previous
//
#include <hip/hip_runtime.h>
#include <math.h>

#define NNODES 100000
#define NEDGES 1600000
#define DD 128
#define BN_EPS 1e-5f
#define SCAN_BLOCKS 98  // ceil(100000 / 1024)

typedef __attribute__((ext_vector_type(8))) short bf16x8;
typedef __attribute__((ext_vector_type(4))) float f32x4;

__device__ __forceinline__ unsigned short f2bf(float f) {  // RNE f32->bf16
  unsigned u = __builtin_bit_cast(unsigned, f);
  u = (u + 0x7fffu + ((u >> 16) & 1u)) >> 16;
  return (unsigned short)u;
}
__device__ __forceinline__ float bf2f(unsigned h) {
  return __builtin_bit_cast(float, h << 16);
}

// ---------------------------------------------------------------------------
// ws layout (bytes):
//   [0,        25.6MB)  xb   bf16 copy of x            [100000][128]
//   [25.6MB,   51.2MB)  h0b  bf16 agg                  [100000][128]
//   [51.2MB,   76.8MB)  h1b  bf16 relu(h0@W1+b1)       [100000][128]
//   [76.8MB, ~84.4MB)   CSR: deg[100000] rowPtr[100004] cursor[100000]
//                            edgeSrc[1600000] blockSums[128] blockOff[128]
//   then: wt1[16384] wt2[16384] (bf16, transposed+swizzled),
//         bnSum[128] bnSq[128] scale[128] shift[128] flag
// ---------------------------------------------------------------------------

// K1 (k_prep): W1/W2 -> bf16 transposed+swizzled; x -> bf16; zero deg/bn; flag.
// wt layout: wt[n*128 + (k ^ ((n&7)<<3))] = W[k][n]  (XOR swizzle on 16B units)
__global__ __launch_bounds__(256) void k_prep(const float* __restrict__ x,
                                              const float* __restrict__ W1,
                                              const float* __restrict__ W2,
                                              unsigned short* __restrict__ xb,
                                              unsigned short* __restrict__ wt1,
                                              unsigned short* __restrict__ wt2,
                                              int* __restrict__ deg,
                                              float* __restrict__ bnAcc,
                                              const int* __restrict__ e32,
                                              int* __restrict__ flag) {
  int bid = blockIdx.x, tid = threadIdx.x;
  if (bid < 2) {
    const float* W = bid ? W2 : W1;
    unsigned short* wt = bid ? wt2 : wt1;
    if (tid < 128) {
      int n = tid;
      for (int k = 0; k < 128; ++k)
        wt[n * 128 + (k ^ ((n & 7) << 3))] = f2bf(W[k * 128 + n]);
    } else {
      // zero bn accumulators (256 floats split across blocks 0/1)
      bnAcc[(bid ? 0 : 128) + (tid - 128)] = 0.f;
      if (bid == 1 && tid == 128) {
        int is64 = 1;
        for (int k = 0; k < 64; ++k) is64 &= (e32[2 * k + 1] == 0);
        *flag = is64;
      }
    }
  } else if (bid < 6252) {  // x -> bf16 : 6250 blocks * 2048 elems
    long j = (long)(bid - 2) * 2048 + tid * 8;
    float4 a = *(const float4*)(x + j);
    float4 b = *(const float4*)(x + j + 4);
    uint4 o;
    o.x = (unsigned)f2bf(a.x) | ((unsigned)f2bf(a.y) << 16);
    o.y = (unsigned)f2bf(a.z) | ((unsigned)f2bf(a.w) << 16);
    o.z = (unsigned)f2bf(b.x) | ((unsigned)f2bf(b.y) << 16);
    o.w = (unsigned)f2bf(b.z) | ((unsigned)f2bf(b.w) << 16);
    *(uint4*)(xb + j) = o;
  } else {  // zero deg: 391 blocks
    int i = (bid - 6252) * 256 + tid;
    if (i < NNODES) deg[i] = 0;
  }
}

// K2: XCD-grouped histogram of dst. group g = blockIdx&7 handles dst range
// [g*12500, (g+1)*12500) so deg atomics stay in one XCD's L2.
__global__ __launch_bounds__(256) void k_count(const int* __restrict__ e32,
                                               int* __restrict__ deg,
                                               const int* __restrict__ flag) {
  int g = blockIdx.x & 7;
  int blk = blockIdx.x >> 3;  // 0..127
  int lo = g * 12500;
  bool f64 = (*flag) != 0;
  const int* dstp = f64 ? (e32 + 2 * (long)NEDGES) : (e32 + NEDGES);
  for (long e = ((long)blk * 256 + threadIdx.x) * 4; e < NEDGES; e += 131072) {
    int d0, d1, d2, d3;
    if (f64) {
      int4 a = *(const int4*)(dstp + 2 * e);
      int4 b = *(const int4*)(dstp + 2 * e + 4);
      d0 = a.x; d1 = a.z; d2 = b.x; d3 = b.z;
    } else {
      int4 a = *(const int4*)(dstp + e);
      d0 = a.x; d1 = a.y; d2 = a.z; d3 = a.w;
    }
    if ((unsigned)(d0 - lo) < 12500u) atomicAdd(&deg[d0], 1);
    if ((unsigned)(d1 - lo) < 12500u) atomicAdd(&deg[d1], 1);
    if ((unsigned)(d2 - lo) < 12500u) atomicAdd(&deg[d2], 1);
    if ((unsigned)(d3 - lo) < 12500u) atomicAdd(&deg[d3], 1);
  }
}

// K3a/b/c: multi-block exclusive scan of deg -> rowPtr, cursor.
__global__ __launch_bounds__(256) void k_scanA(const int4* __restrict__ deg4,
                                               int* __restrict__ blockSums) {
  __shared__ int s[256];
  int tid = threadIdx.x;
  int idx = blockIdx.x * 256 + tid;
  int4 d = {0, 0, 0, 0};
  if (idx < NNODES / 4) d = deg4[idx];
  s[tid] = d.x + d.y + d.z + d.w;
  __syncthreads();
  for (int off = 128; off > 0; off >>= 1) {
    if (tid < off) s[tid] += s[tid + off];
    __syncthreads();
  }
  if (tid == 0) blockSums[blockIdx.x] = s[0];
}

__global__ __launch_bounds__(128) void k_scanB(const int* __restrict__ blockSums,
                                               int* __restrict__ blockOff,
                                               int* __restrict__ rowPtr) {
  __shared__ int s[128];
  int tid = threadIdx.x;
  s[tid] = (tid < SCAN_BLOCKS) ? blockSums[tid] : 0;
  __syncthreads();
  for (int off = 1; off < 128; off <<= 1) {
    int v = (tid >= off) ? s[tid - off] : 0;
    __syncthreads();
    s[tid] += v;
    __syncthreads();
  }
  if (tid < SCAN_BLOCKS) blockOff[tid] = (tid == 0) ? 0 : s[tid - 1];
  if (tid == 0) rowPtr[NNODES] = NEDGES;
}

__global__ __launch_bounds__(256) void k_scanC(const int4* __restrict__ deg4,
                                               const int* __restrict__ blockOff,
                                               int4* __restrict__ rowPtr4,
                                               int4* __restrict__ cursor4) {
  __shared__ int s[256];
  int tid = threadIdx.x;
  int idx = blockIdx.x * 256 + tid;
  int4 d = {0, 0, 0, 0};
  if (idx < NNODES / 4) d = deg4[idx];
  s[tid] = d.x + d.y + d.z + d.w;
  __syncthreads();
  for (int off = 1; off < 256; off <<= 1) {
    int v = (tid >= off) ? s[tid - off] : 0;
    __syncthreads();
    s[tid] += v;
    __syncthreads();
  }
  if (idx < NNODES / 4) {
    int excl = blockOff[blockIdx.x] + ((tid == 0) ? 0 : s[tid - 1]);
    int4 r;
    r.x = excl;
    r.y = r.x + d.x;
    r.z = r.y + d.y;
    r.w = r.z + d.z;
    rowPtr4[idx] = r;
    cursor4[idx] = r;
  }
}

// K4: XCD-grouped CSR fill (same grouping as k_count -> XCD-local writes).
__global__ __launch_bounds__(256) void k_fill(const int* __restrict__ e32,
                                              int* __restrict__ cursor,
                                              int* __restrict__ edgeSrc,
                                              const int* __restrict__ flag) {
  int g = blockIdx.x & 7;
  int blk = blockIdx.x >> 3;
  int lo = g * 12500;
  bool f64 = (*flag) != 0;
  const int* dstp = f64 ? (e32 + 2 * (long)NEDGES) : (e32 + NEDGES);
  for (long e = ((long)blk * 256 + threadIdx.x) * 4; e < NEDGES; e += 131072) {
    int d0, d1, d2, d3;
    if (f64) {
      int4 a = *(const int4*)(dstp + 2 * e);
      int4 b = *(const int4*)(dstp + 2 * e + 4);
      d0 = a.x; d1 = a.z; d2 = b.x; d3 = b.z;
    } else {
      int4 a = *(const int4*)(dstp + e);
      d0 = a.x; d1 = a.y; d2 = a.z; d3 = a.w;
    }
#define FILL1(q, dq)                                            \
    if ((unsigned)((dq) - lo) < 12500u) {                       \
      int s_ = f64 ? e32[2 * (e + q)] : e32[e + q];             \
      int pos_ = atomicAdd(&cursor[dq], 1);                     \
      edgeSrc[pos_] = s_;                                       \
    }
    FILL1(0, d0) FILL1(1, d1) FILL1(2, d2) FILL1(3, d3)
#undef FILL1
  }
}

// K5: gather-accumulate in bf16. One wave per node; lane owns 4B (2 bf16).
__global__ __launch_bounds__(256) void k_gather(const unsigned* __restrict__ xb,
                                                const int* __restrict__ rowPtr,
                                                const int* __restrict__ edgeSrc,
                                                unsigned* __restrict__ h0b) {
  int node = (blockIdx.x * 256 + threadIdx.x) >> 6;
  int lane = threadIdx.x & 63;
  if (node >= NNODES) return;
  long base = (long)node * 64 + lane;
  int beg = rowPtr[node], end = rowPtr[node + 1];
  unsigned u = xb[base];
  float a0 = bf2f(u & 0xffffu), a1 = bf2f(u >> 16);
  int e = beg;
  for (; e + 4 <= end; e += 4) {
    int s0 = edgeSrc[e], s1 = edgeSrc[e + 1], s2 = edgeSrc[e + 2], s3 = edgeSrc[e + 3];
    unsigned v0 = xb[(long)s0 * 64 + lane];
    unsigned v1 = xb[(long)s1 * 64 + lane];
    unsigned v2 = xb[(long)s2 * 64 + lane];
    unsigned v3 = xb[(long)s3 * 64 + lane];
    a0 += bf2f(v0 & 0xffffu) + bf2f(v1 & 0xffffu) + bf2f(v2 & 0xffffu) + bf2f(v3 & 0xffffu);
    a1 += bf2f(v0 >> 16) + bf2f(v1 >> 16) + bf2f(v2 >> 16) + bf2f(v3 >> 16);
  }
  for (; e < end; ++e) {
    unsigned v = xb[(long)edgeSrc[e] * 64 + lane];
    a0 += bf2f(v & 0xffffu);
    a1 += bf2f(v >> 16);
  }
  h0b[base] = (unsigned)f2bf(a0) | ((unsigned)f2bf(a1) << 16);
}

// K6/K7: MFMA GEMM. C = act(A[N,128] @ W[128,128] + bias).
// Block: 128 rows x 128 cols, 4 waves each 64x64 (wr=w>>1, wc=w&1).
// Wave: 4x4 accs of 16x16, K-steps of 32 (mfma_f32_16x16x32_bf16).
// A frags straight from global (each row owned by one wave); W staged in LDS
// (pre-transposed + XOR-swizzled by k_prep): conflict-free ds_read_b128.
// Same k-bijection (k = (lane>>4)*8 + j) used for A and B -> layout-safe.
template <bool RELU, bool BN>
__global__ __launch_bounds__(256) void k_mm(const unsigned short* __restrict__ Ab,
                                            const unsigned short* __restrict__ WtSwz,
                                            const float* __restrict__ bias,
                                            unsigned short* __restrict__ Cb,
                                            float* __restrict__ Cf,
                                            float* __restrict__ bnSum,
                                            float* __restrict__ bnSq) {
  __shared__ unsigned short sW[128 * 128];  // 32 KiB
  __shared__ float sbn[256];
  int tid = threadIdx.x;
#pragma unroll
  for (int i = 0; i < 8; ++i)
    ((uint4*)sW)[tid + 256 * i] = ((const uint4*)WtSwz)[tid + 256 * i];
  if (BN) sbn[tid] = 0.f;
  __syncthreads();

  int w = tid >> 6, lane = tid & 63;
  int wr = w >> 1, wc = w & 1;
  int l4 = lane >> 4, l15 = lane & 15;
  int blkRow = blockIdx.x * 128;

  // preload A fragments: af[mi][ks], row = blkRow + wr*64 + mi*16 + l15
  bf16x8 af[4][4];
#pragma unroll
  for (int mi = 0; mi < 4; ++mi) {
    int r = blkRow + wr * 64 + mi * 16 + l15;
    if (r > NNODES - 1) r = NNODES - 1;  // clamp; results for OOB rows discarded
#pragma unroll
    for (int ks = 0; ks < 4; ++ks)
      af[mi][ks] = *(const bf16x8*)(Ab + (long)r * 128 + ks * 32 + l4 * 8);
  }

  f32x4 acc[4][4];
#pragma unroll
  for (int mi = 0; mi < 4; ++mi)
#pragma unroll
    for (int ni = 0; ni < 4; ++ni) acc[mi][ni] = (f32x4){0.f, 0.f, 0.f, 0.f};

#pragma unroll
  for (int ks = 0; ks < 4; ++ks) {
#pragma unroll
    for (int ni = 0; ni < 4; ++ni) {
      int n = wc * 64 + ni * 16 + l15;
      int k = ks * 32 + l4 * 8;
      bf16x8 bf = *(const bf16x8*)(sW + n * 128 + (k ^ ((n & 7) << 3)));
#pragma unroll
      for (int mi = 0; mi < 4; ++mi)
        acc[mi][ni] = __builtin_amdgcn_mfma_f32_16x16x32_bf16(af[mi][ks], bf,
                                                              acc[mi][ni], 0, 0, 0);
    }
  }

  // epilogue. C/D layout: col = lane&15, row = (lane>>4)*4 + reg.
#pragma unroll
  for (int ni = 0; ni < 4; ++ni) {
    int n = wc * 64 + ni * 16 + l15;
    float bv = bias[n];
    float ls = 0.f, lq = 0.f;
#pragma unroll
    for (int mi = 0; mi < 4; ++mi) {
#pragma unroll
      for (int r = 0; r < 4; ++r) {
        int row = blkRow + wr * 64 + mi * 16 + l4 * 4 + r;
        if (row < NNODES) {
          float v = acc[mi][ni][r] + bv;
          if (RELU) {
            v = fmaxf(v, 0.f);
            Cb[(long)row * 128 + n] = f2bf(v);
          } else {
            Cf[(long)row * 128 + n] = v;
          }
          if (BN) { ls += v; lq += v * v; }
        }
      }
    }
    if (BN) {
      atomicAdd(&sbn[n], ls);
      atomicAdd(&sbn[128 + n], lq);
    }
  }
  if (BN) {
    __syncthreads();
    if (tid < 128) {
      atomicAdd(&bnSum[tid], sbn[tid]);
      atomicAdd(&bnSq[tid], sbn[128 + tid]);
    }
  }
}

// K8: finalize BN.
__global__ void k_bnfin(const float* __restrict__ bnSum, const float* __restrict__ bnSq,
                        const float* __restrict__ gamma, const float* __restrict__ beta,
                        float* __restrict__ scale, float* __restrict__ shift) {
  int c = threadIdx.x;
  float m = bnSum[c] * (1.0f / NNODES);
  float var = bnSq[c] * (1.0f / NNODES) - m * m;
  float sc = gamma[c] * rsqrtf(var + BN_EPS);
  scale[c] = sc;
  shift[c] = beta[c] - m * sc;
}

// K9: out = h2*scale + shift + x.
__global__ __launch_bounds__(256) void k_epi(const float4* __restrict__ h2,
                                             const float4* __restrict__ x4,
                                             const float4* __restrict__ scale4,
                                             const float4* __restrict__ shift4,
                                             float4* __restrict__ out4) {
  long i = (long)blockIdx.x * 256 + threadIdx.x;
  if (i >= (long)NNODES * 32) return;
  int c = (int)(i & 31);
  float4 h = h2[i], xx = x4[i], sc = scale4[c], sh = shift4[c];
  float4 o;
  o.x = fmaf(h.x, sc.x, sh.x) + xx.x;
  o.y = fmaf(h.y, sc.y, sh.y) + xx.y;
  o.z = fmaf(h.z, sc.z, sh.z) + xx.z;
  o.w = fmaf(h.w, sc.w, sh.w) + xx.w;
  out4[i] = o;
}

extern "C" void kernel_launch(void* const* d_in, const int* in_sizes, int n_in,
                              void* d_out, int out_size, void* d_ws, size_t ws_size,
                              hipStream_t stream) {
  const float* x     = (const float*)d_in[0];
  const int*   e32   = (const int*)d_in[1];
  const float* W1    = (const float*)d_in[2];
  const float* b1    = (const float*)d_in[3];
  const float* W2    = (const float*)d_in[4];
  const float* b2    = (const float*)d_in[5];
  const float* gamma = (const float*)d_in[6];
  const float* beta  = (const float*)d_in[7];
  float* out = (float*)d_out;

  char* ws = (char*)d_ws;
  const size_t BFB = (size_t)NNODES * DD * 2;  // 25.6 MB per bf16 buffer
  unsigned short* xb  = (unsigned short*)ws;
  unsigned short* h0b = (unsigned short*)(ws + BFB);
  unsigned short* h1b = (unsigned short*)(ws + 2 * BFB);

  int* deg       = (int*)(ws + 3 * BFB);
  int* rowPtr    = deg + NNODES;         // [NNODES+4] (16B-aligned blocks)
  int* cursor    = rowPtr + NNODES + 4;
  int* edgeSrc   = cursor + NNODES;
  int* blockSums = edgeSrc + NEDGES;
  int* blockOff  = blockSums + 128;

  unsigned short* wt1 = (unsigned short*)(blockOff + 128);
  unsigned short* wt2 = wt1 + 16384;
  float* bnSum = (float*)(wt2 + 16384);
  float* bnSq  = bnSum + 128;
  float* scale = bnSum + 256;
  float* shift = bnSum + 384;
  int*   flag  = (int*)(bnSum + 512);

  k_prep<<<6643, 256, 0, stream>>>(x, W1, W2, xb, wt1, wt2, deg, bnSum, e32, flag);
  k_count<<<1024, 256, 0, stream>>>(e32, deg, flag);
  k_scanA<<<SCAN_BLOCKS, 256, 0, stream>>>((const int4*)deg, blockSums);
  k_scanB<<<1, 128, 0, stream>>>(blockSums, blockOff, rowPtr);
  k_scanC<<<SCAN_BLOCKS, 256, 0, stream>>>((const int4*)deg, blockOff,
                                           (int4*)rowPtr, (int4*)cursor);
  k_fill<<<1024, 256, 0, stream>>>(e32, cursor, edgeSrc, flag);
  k_gather<<<25000, 256, 0, stream>>>((const unsigned*)xb, rowPtr, edgeSrc,
                                      (unsigned*)h0b);
  k_mm<true, false><<<782, 256, 0, stream>>>(h0b, wt1, b1, h1b, nullptr,
                                             nullptr, nullptr);
  k_mm<false, true><<<782, 256, 0, stream>>>(h1b, wt2, b2, nullptr, out,
                                             bnSum, bnSq);
  k_bnfin<<<1, 128, 0, stream>>>(bnSum, bnSq, gamma, beta, scale, shift);
  k_epi<<<12500, 256, 0, stream>>>((const float4*)out, (const float4*)x,
                                   (const float4*)scale, (const float4*)shift,
                                   (float4*)out);
}

// Round 5
// 269.907 us; speedup vs baseline: 10.7498x; 1.2863x over previous
//
#include <hip/hip_runtime.h>
#include <math.h>

#define NNODES 100000
#define NEDGES 1600000
#define DD 128
#define BN_EPS 1e-5f

#define NBUCK 98     // ceil(100000/1024)
#define BUCKW 1024   // dsts per bucket (aligned: bucket = dst>>10)
#define PBLK 512     // partition blocks
#define PCHUNK 3125  // edges per partition block (512*3125 = 1.6M exact)

typedef __attribute__((ext_vector_type(8))) short bf16x8;
typedef __attribute__((ext_vector_type(4))) float f32x4;

__device__ __forceinline__ unsigned short f2bf(float f) {  // RNE f32->bf16
  unsigned u = __builtin_bit_cast(unsigned, f);
  u = (u + 0x7fffu + ((u >> 16) & 1u)) >> 16;
  return (unsigned short)u;
}
__device__ __forceinline__ float bf2f(unsigned h) {
  return __builtin_bit_cast(float, h << 16);
}

// ---------------------------------------------------------------------------
// ws layout:
//   xb   [100000][128] bf16                           25.6 MB
//   h0b  [100000][128] bf16  (agg; later reused as h2b = GEMM2 out)
//   h1b  [100000][128] bf16  (relu(h0@W1+b1))
//   rowPtr[100004] | edgeSrc[1.6M] | stage[1.6M] | cnt[98*512] | off[98*512]
//   bucketTot[128] | bucketBase[128] | wt1[16384] wt2[16384] (bf16)
//   bnSum[128] bnSq[128] scale[128] shift[128] flag
// ---------------------------------------------------------------------------

// K1: W1/W2 -> bf16 transposed+swizzled; x -> bf16; zero bn/bucketTot; flag.
// wt layout: wt[n*128 + (k ^ ((n&7)<<3))] = W[k][n]
__global__ __launch_bounds__(256) void k_prep(const float* __restrict__ x,
                                              const float* __restrict__ W1,
                                              const float* __restrict__ W2,
                                              unsigned short* __restrict__ xb,
                                              unsigned short* __restrict__ wt1,
                                              unsigned short* __restrict__ wt2,
                                              int* __restrict__ bucketTot,
                                              float* __restrict__ bnAcc,
                                              const int* __restrict__ e32,
                                              int* __restrict__ flag) {
  int bid = blockIdx.x, tid = threadIdx.x;
  if (bid < 2) {
    const float* W = bid ? W2 : W1;
    unsigned short* wt = bid ? wt2 : wt1;
    if (tid < 128) {
      int n = tid;
      for (int k = 0; k < 128; ++k)
        wt[n * 128 + (k ^ ((n & 7) << 3))] = f2bf(W[k * 128 + n]);
    } else {
      bnAcc[(bid ? 0 : 128) + (tid - 128)] = 0.f;  // bnSum / bnSq halves
      if (bid == 0) bucketTot[tid - 128] = 0;
      if (bid == 1 && tid == 128) {
        int is64 = 1;
        for (int k = 0; k < 64; ++k) is64 &= (e32[2 * k + 1] == 0);
        *flag = is64;
      }
    }
  } else {  // x -> bf16 : 6250 blocks * 2048 elems
    long j = (long)(bid - 2) * 2048 + tid * 8;
    float4 a = *(const float4*)(x + j);
    float4 b = *(const float4*)(x + j + 4);
    uint4 o;
    o.x = (unsigned)f2bf(a.x) | ((unsigned)f2bf(a.y) << 16);
    o.y = (unsigned)f2bf(a.z) | ((unsigned)f2bf(a.w) << 16);
    o.z = (unsigned)f2bf(b.x) | ((unsigned)f2bf(b.y) << 16);
    o.w = (unsigned)f2bf(b.z) | ((unsigned)f2bf(b.w) << 16);
    *(uint4*)(xb + j) = o;
  }
}

// K2: per-(block,bucket) histogram. Contiguous writes only.
__global__ __launch_bounds__(256) void k_pcount(const int* __restrict__ e32,
                                                const int* __restrict__ flag,
                                                int* __restrict__ cnt,
                                                int* __restrict__ bucketTot) {
  __shared__ int sc[NBUCK];
  int tid = threadIdx.x, blk = blockIdx.x;
  for (int i = tid; i < NBUCK; i += 256) sc[i] = 0;
  __syncthreads();
  bool f64 = (*flag) != 0;
  const int* dstp = f64 ? (e32 + 2 * (long)NEDGES) : (e32 + NEDGES);
  long e0 = (long)blk * PCHUNK;
  for (int i = tid; i < PCHUNK; i += 256) {
    long e = e0 + i;
    int d = f64 ? dstp[2 * e] : dstp[e];
    atomicAdd(&sc[d >> 10], 1);
  }
  __syncthreads();
  for (int i = tid; i < NBUCK; i += 256) {
    cnt[i * PBLK + blk] = sc[i];
    atomicAdd(&bucketTot[i], sc[i]);
  }
}

// K3: exclusive scan of 98 bucket totals -> bucketBase; set rowPtr[N].
__global__ __launch_bounds__(128) void k_bscan(const int* __restrict__ bucketTot,
                                               int* __restrict__ bucketBase,
                                               int* __restrict__ rowPtr) {
  __shared__ int s[128];
  int tid = threadIdx.x;
  s[tid] = (tid < NBUCK) ? bucketTot[tid] : 0;
  __syncthreads();
  for (int o = 1; o < 128; o <<= 1) {
    int v = (tid >= o) ? s[tid - o] : 0;
    __syncthreads();
    s[tid] += v;
    __syncthreads();
  }
  if (tid < NBUCK) bucketBase[tid] = (tid == 0) ? 0 : s[tid - 1];
  if (tid == 0) rowPtr[NNODES] = NEDGES;
}

// K4: per-bucket scan over 512 block counts -> off[bucket][block].
__global__ __launch_bounds__(256) void k_pscan(const int* __restrict__ cnt,
                                               const int* __restrict__ bucketBase,
                                               int* __restrict__ off) {
  __shared__ int s[256];
  int b = blockIdx.x, tid = threadIdx.x;
  int v0 = cnt[b * PBLK + 2 * tid], v1 = cnt[b * PBLK + 2 * tid + 1];
  s[tid] = v0 + v1;
  __syncthreads();
  for (int o = 1; o < 256; o <<= 1) {
    int v = (tid >= o) ? s[tid - o] : 0;
    __syncthreads();
    s[tid] += v;
    __syncthreads();
  }
  int excl = s[tid] - v0 - v1;
  int base = bucketBase[b];
  off[b * PBLK + 2 * tid]     = base + excl;
  off[b * PBLK + 2 * tid + 1] = base + excl + v0;
}

// K5: partition edges into bucket-major stage, packed (src<<10)|dstLocal.
// Each block's writes per bucket are dense runs in a private range.
__global__ __launch_bounds__(256) void k_ppart(const int* __restrict__ e32,
                                               const int* __restrict__ flag,
                                               const int* __restrict__ off,
                                               unsigned* __restrict__ stage) {
  __shared__ int cur[NBUCK];
  int tid = threadIdx.x, blk = blockIdx.x;
  if (tid < NBUCK) cur[tid] = off[tid * PBLK + blk];
  __syncthreads();
  bool f64 = (*flag) != 0;
  const int* dstp = f64 ? (e32 + 2 * (long)NEDGES) : (e32 + NEDGES);
  long e0 = (long)blk * PCHUNK;
  for (int i = tid; i < PCHUNK; i += 256) {
    long e = e0 + i;
    int d = f64 ? dstp[2 * e] : dstp[e];
    int sv = f64 ? e32[2 * e] : e32[e];
    int pos = atomicAdd(&cur[d >> 10], 1);
    stage[pos] = ((unsigned)sv << 10) | (unsigned)(d & (BUCKW - 1));
  }
}

// K6: one block per bucket: LDS histogram -> LDS scan -> contiguous rowPtr
// write; then place edgeSrc within the bucket's small window.
__global__ __launch_bounds__(256) void k_bucket(const unsigned* __restrict__ stage,
                                                const int* __restrict__ bucketBase,
                                                const int* __restrict__ bucketTot,
                                                int* __restrict__ rowPtr,
                                                int* __restrict__ edgeSrc) {
  __shared__ int sdeg[BUCKW];
  __shared__ int srow[BUCKW];
  __shared__ int ss[256];
  int b = blockIdx.x, tid = threadIdx.x;
  int base = bucketBase[b], tot = bucketTot[b];
  for (int i = tid; i < BUCKW; i += 256) sdeg[i] = 0;
  __syncthreads();
  const unsigned* st = stage + base;
  for (int i = tid; i < tot; i += 256) atomicAdd(&sdeg[st[i] & (BUCKW - 1)], 1);
  __syncthreads();
  int j = tid * 4;
  int d0 = sdeg[j], d1 = sdeg[j + 1], d2 = sdeg[j + 2], d3 = sdeg[j + 3];
  int tsum = d0 + d1 + d2 + d3;
  ss[tid] = tsum;
  __syncthreads();
  for (int o = 1; o < 256; o <<= 1) {
    int v = (tid >= o) ? ss[tid - o] : 0;
    __syncthreads();
    ss[tid] += v;
    __syncthreads();
  }
  int excl = ss[tid] - tsum;
  srow[j] = excl;
  srow[j + 1] = excl + d0;
  srow[j + 2] = excl + d0 + d1;
  srow[j + 3] = excl + d0 + d1 + d2;
  __syncthreads();
  for (int i = tid; i < BUCKW; i += 256) {
    int dst = b * BUCKW + i;
    if (dst < NNODES) rowPtr[dst] = base + srow[i];
    sdeg[i] = srow[i];  // reuse as cursor
  }
  __syncthreads();
  for (int i = tid; i < tot; i += 256) {
    unsigned p = st[i];
    int pos = atomicAdd(&sdeg[p & (BUCKW - 1)], 1);
    edgeSrc[base + pos] = (int)(p >> 10);
  }
}

// K7: gather-accumulate in bf16. One wave per node; lane owns 4B (2 bf16).
__global__ __launch_bounds__(256) void k_gather(const unsigned* __restrict__ xb,
                                                const int* __restrict__ rowPtr,
                                                const int* __restrict__ edgeSrc,
                                                unsigned* __restrict__ h0b) {
  int node = (blockIdx.x * 256 + threadIdx.x) >> 6;
  int lane = threadIdx.x & 63;
  if (node >= NNODES) return;
  long base = (long)node * 64 + lane;
  int beg = rowPtr[node], end = rowPtr[node + 1];
  unsigned u = xb[base];
  float a0 = bf2f(u & 0xffffu), a1 = bf2f(u >> 16);
  int e = beg;
  for (; e + 4 <= end; e += 4) {
    int s0 = edgeSrc[e], s1 = edgeSrc[e + 1], s2 = edgeSrc[e + 2], s3 = edgeSrc[e + 3];
    unsigned v0 = xb[(long)s0 * 64 + lane];
    unsigned v1 = xb[(long)s1 * 64 + lane];
    unsigned v2 = xb[(long)s2 * 64 + lane];
    unsigned v3 = xb[(long)s3 * 64 + lane];
    a0 += bf2f(v0 & 0xffffu) + bf2f(v1 & 0xffffu) + bf2f(v2 & 0xffffu) + bf2f(v3 & 0xffffu);
    a1 += bf2f(v0 >> 16) + bf2f(v1 >> 16) + bf2f(v2 >> 16) + bf2f(v3 >> 16);
  }
  for (; e < end; ++e) {
    unsigned v = xb[(long)edgeSrc[e] * 64 + lane];
    a0 += bf2f(v & 0xffffu);
    a1 += bf2f(v >> 16);
  }
  h0b[base] = (unsigned)f2bf(a0) | ((unsigned)f2bf(a1) << 16);
}

// K8/K9: MFMA GEMM, 128x128 block, 4 waves of 64x64; bf16 out both layers.
template <bool RELU, bool BN>
__global__ __launch_bounds__(256) void k_mm(const unsigned short* __restrict__ Ab,
                                            const unsigned short* __restrict__ WtSwz,
                                            const float* __restrict__ bias,
                                            unsigned short* __restrict__ Cb,
                                            float* __restrict__ bnSum,
                                            float* __restrict__ bnSq) {
  __shared__ unsigned short sW[128 * 128];
  __shared__ float sbn[256];
  int tid = threadIdx.x;
#pragma unroll
  for (int i = 0; i < 8; ++i)
    ((uint4*)sW)[tid + 256 * i] = ((const uint4*)WtSwz)[tid + 256 * i];
  if (BN) sbn[tid] = 0.f;
  __syncthreads();

  int w = tid >> 6, lane = tid & 63;
  int wr = w >> 1, wc = w & 1;
  int l4 = lane >> 4, l15 = lane & 15;
  int blkRow = blockIdx.x * 128;

  bf16x8 af[4][4];
#pragma unroll
  for (int mi = 0; mi < 4; ++mi) {
    int r = blkRow + wr * 64 + mi * 16 + l15;
    if (r > NNODES - 1) r = NNODES - 1;
#pragma unroll
    for (int ks = 0; ks < 4; ++ks)
      af[mi][ks] = *(const bf16x8*)(Ab + (long)r * 128 + ks * 32 + l4 * 8);
  }

  f32x4 acc[4][4];
#pragma unroll
  for (int mi = 0; mi < 4; ++mi)
#pragma unroll
    for (int ni = 0; ni < 4; ++ni) acc[mi][ni] = (f32x4){0.f, 0.f, 0.f, 0.f};

#pragma unroll
  for (int ks = 0; ks < 4; ++ks) {
#pragma unroll
    for (int ni = 0; ni < 4; ++ni) {
      int n = wc * 64 + ni * 16 + l15;
      int k = ks * 32 + l4 * 8;
      bf16x8 bf = *(const bf16x8*)(sW + n * 128 + (k ^ ((n & 7) << 3)));
#pragma unroll
      for (int mi = 0; mi < 4; ++mi)
        acc[mi][ni] = __builtin_amdgcn_mfma_f32_16x16x32_bf16(af[mi][ks], bf,
                                                              acc[mi][ni], 0, 0, 0);
    }
  }

#pragma unroll
  for (int ni = 0; ni < 4; ++ni) {
    int n = wc * 64 + ni * 16 + l15;
    float bv = bias[n];
    float ls = 0.f, lq = 0.f;
#pragma unroll
    for (int mi = 0; mi < 4; ++mi) {
#pragma unroll
      for (int r = 0; r < 4; ++r) {
        int row = blkRow + wr * 64 + mi * 16 + l4 * 4 + r;
        if (row < NNODES) {
          float v = acc[mi][ni][r] + bv;
          if (RELU) v = fmaxf(v, 0.f);
          Cb[(long)row * 128 + n] = f2bf(v);
          if (BN) { ls += v; lq += v * v; }
        }
      }
    }
    if (BN) {
      atomicAdd(&sbn[n], ls);
      atomicAdd(&sbn[128 + n], lq);
    }
  }
  if (BN) {
    __syncthreads();
    if (tid < 128) {
      atomicAdd(&bnSum[tid], sbn[tid]);
      atomicAdd(&bnSq[tid], sbn[128 + tid]);
    }
  }
}

// K10: finalize BN.
__global__ void k_bnfin(const float* __restrict__ bnSum, const float* __restrict__ bnSq,
                        const float* __restrict__ gamma, const float* __restrict__ beta,
                        float* __restrict__ scale, float* __restrict__ shift) {
  int c = threadIdx.x;
  float m = bnSum[c] * (1.0f / NNODES);
  float var = bnSq[c] * (1.0f / NNODES) - m * m;
  float sc = gamma[c] * rsqrtf(var + BN_EPS);
  scale[c] = sc;
  shift[c] = beta[c] - m * sc;
}

// K11: out = h2b*scale + shift + x. 8 elems/thread.
__global__ __launch_bounds__(256) void k_epi(const uint4* __restrict__ h2b4,
                                             const float4* __restrict__ x4,
                                             const float4* __restrict__ scale4,
                                             const float4* __restrict__ shift4,
                                             float4* __restrict__ out4) {
  long j = (long)blockIdx.x * 256 + threadIdx.x;  // unit of 8 elems
  int c4 = (int)((j * 8) & 127) >> 2;             // float4 col index (even)
  uint4 h = h2b4[j];
  float4 xa = x4[2 * j], xc = x4[2 * j + 1];
  float4 sa = scale4[c4], sb = scale4[c4 + 1];
  float4 fa = shift4[c4], fb = shift4[c4 + 1];
  float4 oa, ob;
  oa.x = fmaf(bf2f(h.x & 0xffffu), sa.x, fa.x) + xa.x;
  oa.y = fmaf(bf2f(h.x >> 16),     sa.y, fa.y) + xa.y;
  oa.z = fmaf(bf2f(h.y & 0xffffu), sa.z, fa.z) + xa.z;
  oa.w = fmaf(bf2f(h.y >> 16),     sa.w, fa.w) + xa.w;
  ob.x = fmaf(bf2f(h.z & 0xffffu), sb.x, fb.x) + xc.x;
  ob.y = fmaf(bf2f(h.z >> 16),     sb.y, fb.y) + xc.y;
  ob.z = fmaf(bf2f(h.w & 0xffffu), sb.z, fb.z) + xc.z;
  ob.w = fmaf(bf2f(h.w >> 16),     sb.w, fb.w) + xc.w;
  out4[2 * j] = oa;
  out4[2 * j + 1] = ob;
}

extern "C" void kernel_launch(void* const* d_in, const int* in_sizes, int n_in,
                              void* d_out, int out_size, void* d_ws, size_t ws_size,
                              hipStream_t stream) {
  const float* x     = (const float*)d_in[0];
  const int*   e32   = (const int*)d_in[1];
  const float* W1    = (const float*)d_in[2];
  const float* b1    = (const float*)d_in[3];
  const float* W2    = (const float*)d_in[4];
  const float* b2    = (const float*)d_in[5];
  const float* gamma = (const float*)d_in[6];
  const float* beta  = (const float*)d_in[7];
  float* out = (float*)d_out;

  char* ws = (char*)d_ws;
  const size_t BFB = (size_t)NNODES * DD * 2;  // 25.6 MB
  unsigned short* xb  = (unsigned short*)ws;
  unsigned short* h0b = (unsigned short*)(ws + BFB);   // later h2b
  unsigned short* h1b = (unsigned short*)(ws + 2 * BFB);
  unsigned short* h2b = h0b;  // GEMM2 out reuses h0b (dead after GEMM1)

  int* rowPtr     = (int*)(ws + 3 * BFB);        // [NNODES+4]
  int* edgeSrc    = rowPtr + NNODES + 4;         // [NEDGES]
  unsigned* stage = (unsigned*)(edgeSrc + NEDGES);  // [NEDGES]
  int* cnt        = (int*)(stage + NEDGES);      // [NBUCK*PBLK]
  int* off        = cnt + NBUCK * PBLK;          // [NBUCK*PBLK]
  int* bucketTot  = off + NBUCK * PBLK;          // [128]
  int* bucketBase = bucketTot + 128;             // [128]

  unsigned short* wt1 = (unsigned short*)(bucketBase + 128);
  unsigned short* wt2 = wt1 + 16384;
  float* bnSum = (float*)(wt2 + 16384);
  float* bnSq  = bnSum + 128;
  float* scale = bnSum + 256;
  float* shift = bnSum + 384;
  int*   flag  = (int*)(bnSum + 512);

  k_prep<<<6252, 256, 0, stream>>>(x, W1, W2, xb, wt1, wt2, bucketTot, bnSum,
                                   e32, flag);
  k_pcount<<<PBLK, 256, 0, stream>>>(e32, flag, cnt, bucketTot);
  k_bscan<<<1, 128, 0, stream>>>(bucketTot, bucketBase, rowPtr);
  k_pscan<<<NBUCK, 256, 0, stream>>>(cnt, bucketBase, off);
  k_ppart<<<PBLK, 256, 0, stream>>>(e32, flag, off, stage);
  k_bucket<<<NBUCK, 256, 0, stream>>>(stage, bucketBase, bucketTot, rowPtr,
                                      edgeSrc);
  k_gather<<<25000, 256, 0, stream>>>((const unsigned*)xb, rowPtr, edgeSrc,
                                      (unsigned*)h0b);
  k_mm<true, false><<<782, 256, 0, stream>>>(h0b, wt1, b1, h1b, nullptr,
                                             nullptr);
  k_mm<false, true><<<782, 256, 0, stream>>>(h1b, wt2, b2, h2b, bnSum, bnSq);
  k_bnfin<<<1, 128, 0, stream>>>(bnSum, bnSq, gamma, beta, scale, shift);
  k_epi<<<6250, 256, 0, stream>>>((const uint4*)h2b, (const float4*)x,
                                  (const float4*)scale, (const float4*)shift,
                                  (float4*)out);
}

// Round 6
// 254.230 us; speedup vs baseline: 11.4127x; 1.0617x over previous
//
#include <hip/hip_runtime.h>
#include <math.h>

#define NNODES 100000
#define NEDGES 1600000
#define DD 128
#define BN_EPS 1e-5f

#define NBUCK 98     // ceil(100000/1024)
#define BUCKW 1024   // dsts per bucket (bucket = dst>>10)
#define PBLK 512     // partition blocks
#define PCHUNK 3125  // edges per partition block (512*3125 = 1.6M exact)

typedef __attribute__((ext_vector_type(8))) short bf16x8;
typedef __attribute__((ext_vector_type(4))) float f32x4;

__device__ __forceinline__ unsigned short f2bf(float f) {  // RNE f32->bf16
  unsigned u = __builtin_bit_cast(unsigned, f);
  u = (u + 0x7fffu + ((u >> 16) & 1u)) >> 16;
  return (unsigned short)u;
}
__device__ __forceinline__ float bf2f(unsigned h) {
  return __builtin_bit_cast(float, h << 16);
}
__device__ __forceinline__ float bfLO(unsigned u) {
  return __builtin_bit_cast(float, u << 16);
}
__device__ __forceinline__ float bfHI(unsigned u) {
  return __builtin_bit_cast(float, u & 0xffff0000u);
}

// ---------------------------------------------------------------------------
// ws layout:
//   xb   [100000][128] bf16   25.6 MB
//   h0b  [100000][128] bf16   (agg; reused as h2b = GEMM2 out)
//   h1b  [100000][128] bf16
//   rowPtr[100004] | edgeSrc[1.6M] | stage[1.6M] | cnt[98*512] | off[98*512]
//   bucketTot[128] | bucketBase[128] | wt1[16384] wt2[16384] (bf16)
//   bnSum[128] bnSq[128]
// ---------------------------------------------------------------------------

// K1: fused prep. blocks 0-1: W->bf16 transposed+swizzled + zero bn.
// blocks 2..6251: x->bf16. blocks 6252..6763: per-(block,bucket) histogram.
__global__ __launch_bounds__(256) void k_prep(const float* __restrict__ x,
                                              const float* __restrict__ W1,
                                              const float* __restrict__ W2,
                                              unsigned short* __restrict__ xb,
                                              unsigned short* __restrict__ wt1,
                                              unsigned short* __restrict__ wt2,
                                              float* __restrict__ bnAcc,
                                              const int* __restrict__ e32,
                                              int* __restrict__ cnt) {
  __shared__ int sc[NBUCK];
  int bid = blockIdx.x, tid = threadIdx.x;
  if (bid < 2) {
    const float* W = bid ? W2 : W1;
    unsigned short* wt = bid ? wt2 : wt1;
    if (tid < 128) {
      int n = tid;
      for (int k = 0; k < 128; ++k)
        wt[n * 128 + (k ^ ((n & 7) << 3))] = f2bf(W[k * 128 + n]);
    } else {
      bnAcc[(bid ? 0 : 128) + (tid - 128)] = 0.f;  // bnSum / bnSq halves
    }
  } else if (bid < 6252) {  // x -> bf16 : 6250 blocks * 2048 elems
    long j = (long)(bid - 2) * 2048 + tid * 8;
    float4 a = *(const float4*)(x + j);
    float4 b = *(const float4*)(x + j + 4);
    uint4 o;
    o.x = (unsigned)f2bf(a.x) | ((unsigned)f2bf(a.y) << 16);
    o.y = (unsigned)f2bf(a.z) | ((unsigned)f2bf(a.w) << 16);
    o.z = (unsigned)f2bf(b.x) | ((unsigned)f2bf(b.y) << 16);
    o.w = (unsigned)f2bf(b.z) | ((unsigned)f2bf(b.w) << 16);
    *(uint4*)(xb + j) = o;
  } else {  // pcount
    int blk = bid - 6252;
    int z = (tid < 64) ? (e32[2 * tid + 1] == 0) : 1;
    int is64 = __syncthreads_and(z);
    for (int i = tid; i < NBUCK; i += 256) sc[i] = 0;
    __syncthreads();
    const int* dstp = is64 ? (e32 + 2 * (long)NEDGES) : (e32 + NEDGES);
    long e0 = (long)blk * PCHUNK;
    for (int i = tid; i < PCHUNK; i += 256) {
      long e = e0 + i;
      int d = is64 ? dstp[2 * e] : dstp[e];
      atomicAdd(&sc[d >> 10], 1);
    }
    __syncthreads();
    for (int i = tid; i < NBUCK; i += 256) cnt[i * PBLK + blk] = sc[i];
  }
}

// K2: per-bucket local scan of 512 block counts -> off (local), bucketTot.
__global__ __launch_bounds__(256) void k_lscan(const int* __restrict__ cnt,
                                               int* __restrict__ off,
                                               int* __restrict__ bucketTot) {
  __shared__ int s[256];
  int b = blockIdx.x, tid = threadIdx.x;
  int v0 = cnt[b * PBLK + 2 * tid], v1 = cnt[b * PBLK + 2 * tid + 1];
  s[tid] = v0 + v1;
  __syncthreads();
  for (int o = 1; o < 256; o <<= 1) {
    int v = (tid >= o) ? s[tid - o] : 0;
    __syncthreads();
    s[tid] += v;
    __syncthreads();
  }
  int excl = s[tid] - v0 - v1;
  off[b * PBLK + 2 * tid] = excl;
  off[b * PBLK + 2 * tid + 1] = excl + v0;
  if (tid == 255) bucketTot[b] = s[255];
}

// K3: exclusive scan of 98 bucket totals -> bucketBase; set rowPtr[N].
__global__ __launch_bounds__(128) void k_bscan(const int* __restrict__ bucketTot,
                                               int* __restrict__ bucketBase,
                                               int* __restrict__ rowPtr) {
  __shared__ int s[128];
  int tid = threadIdx.x;
  s[tid] = (tid < NBUCK) ? bucketTot[tid] : 0;
  __syncthreads();
  for (int o = 1; o < 128; o <<= 1) {
    int v = (tid >= o) ? s[tid - o] : 0;
    __syncthreads();
    s[tid] += v;
    __syncthreads();
  }
  if (tid < NBUCK) bucketBase[tid] = (tid == 0) ? 0 : s[tid - 1];
  if (tid == 0) rowPtr[NNODES] = NEDGES;
}

// K4: partition edges into bucket-major stage, packed (src<<10)|dstLocal.
__global__ __launch_bounds__(256) void k_ppart(const int* __restrict__ e32,
                                               const int* __restrict__ off,
                                               const int* __restrict__ bucketBase,
                                               unsigned* __restrict__ stage) {
  __shared__ int cur[NBUCK];
  int tid = threadIdx.x, blk = blockIdx.x;
  int z = (tid < 64) ? (e32[2 * tid + 1] == 0) : 1;
  int is64 = __syncthreads_and(z);
  if (tid < NBUCK) cur[tid] = off[tid * PBLK + blk] + bucketBase[tid];
  __syncthreads();
  const int* dstp = is64 ? (e32 + 2 * (long)NEDGES) : (e32 + NEDGES);
  long e0 = (long)blk * PCHUNK;
  for (int i = tid; i < PCHUNK; i += 256) {
    long e = e0 + i;
    int d = is64 ? dstp[2 * e] : dstp[e];
    int sv = is64 ? e32[2 * e] : e32[e];
    int pos = atomicAdd(&cur[d >> 10], 1);
    stage[pos] = ((unsigned)sv << 10) | (unsigned)(d & (BUCKW - 1));
  }
}

// K5: one block per bucket: LDS histogram -> scan -> rowPtr; place edgeSrc.
__global__ __launch_bounds__(256) void k_bucket(const unsigned* __restrict__ stage,
                                                const int* __restrict__ bucketBase,
                                                const int* __restrict__ bucketTot,
                                                int* __restrict__ rowPtr,
                                                int* __restrict__ edgeSrc) {
  __shared__ int sdeg[BUCKW];
  __shared__ int srow[BUCKW];
  __shared__ int ss[256];
  int b = blockIdx.x, tid = threadIdx.x;
  int base = bucketBase[b], tot = bucketTot[b];
  for (int i = tid; i < BUCKW; i += 256) sdeg[i] = 0;
  __syncthreads();
  const unsigned* st = stage + base;
  for (int i = tid; i < tot; i += 256) atomicAdd(&sdeg[st[i] & (BUCKW - 1)], 1);
  __syncthreads();
  int j = tid * 4;
  int d0 = sdeg[j], d1 = sdeg[j + 1], d2 = sdeg[j + 2], d3 = sdeg[j + 3];
  int tsum = d0 + d1 + d2 + d3;
  ss[tid] = tsum;
  __syncthreads();
  for (int o = 1; o < 256; o <<= 1) {
    int v = (tid >= o) ? ss[tid - o] : 0;
    __syncthreads();
    ss[tid] += v;
    __syncthreads();
  }
  int excl = ss[tid] - tsum;
  srow[j] = excl;
  srow[j + 1] = excl + d0;
  srow[j + 2] = excl + d0 + d1;
  srow[j + 3] = excl + d0 + d1 + d2;
  __syncthreads();
  for (int i = tid; i < BUCKW; i += 256) {
    int dst = b * BUCKW + i;
    if (dst < NNODES) rowPtr[dst] = base + srow[i];
    sdeg[i] = srow[i];  // reuse as cursor
  }
  __syncthreads();
  for (int i = tid; i < tot; i += 256) {
    unsigned p = st[i];
    int pos = atomicAdd(&sdeg[p & (BUCKW - 1)], 1);
    edgeSrc[base + pos] = (int)(p >> 10);
  }
}

// K6: gather at 8B/lane. Wave = 1 node; lanes 0-31 edge e, lanes 32-63 e+1.
__global__ __launch_bounds__(256) void k_gather(const uint2* __restrict__ xb2,
                                                const int* __restrict__ rowPtr,
                                                const int* __restrict__ edgeSrc,
                                                uint2* __restrict__ h0b2) {
  int node = (blockIdx.x * 256 + threadIdx.x) >> 6;
  int lane = threadIdx.x & 63;
  if (node >= NNODES) return;
  int li = lane & 31, half = lane >> 5;
  int beg = rowPtr[node], end = rowPtr[node + 1];
  float a0 = 0.f, a1 = 0.f, a2 = 0.f, a3 = 0.f;
  if (half == 0) {  // init from own row
    uint2 u = xb2[(long)node * 32 + li];
    a0 = bfLO(u.x); a1 = bfHI(u.x); a2 = bfLO(u.y); a3 = bfHI(u.y);
  }
  int e = beg;
  for (; e + 4 <= end; e += 4) {
    int sA_ = edgeSrc[e + half];
    int sB_ = edgeSrc[e + 2 + half];
    uint2 va = xb2[(long)sA_ * 32 + li];
    uint2 vb = xb2[(long)sB_ * 32 + li];
    a0 += bfLO(va.x); a1 += bfHI(va.x); a2 += bfLO(va.y); a3 += bfHI(va.y);
    a0 += bfLO(vb.x); a1 += bfHI(vb.x); a2 += bfLO(vb.y); a3 += bfHI(vb.y);
  }
  if (e + 2 <= end) {
    int s_ = edgeSrc[e + half];
    uint2 v = xb2[(long)s_ * 32 + li];
    a0 += bfLO(v.x); a1 += bfHI(v.x); a2 += bfLO(v.y); a3 += bfHI(v.y);
    e += 2;
  }
  if (e < end && half == 0) {  // odd tail: lower half only
    int s_ = edgeSrc[e];
    uint2 v = xb2[(long)s_ * 32 + li];
    a0 += bfLO(v.x); a1 += bfHI(v.x); a2 += bfLO(v.y); a3 += bfHI(v.y);
  }
  a0 += __shfl_xor(a0, 32, 64);
  a1 += __shfl_xor(a1, 32, 64);
  a2 += __shfl_xor(a2, 32, 64);
  a3 += __shfl_xor(a3, 32, 64);
  if (half == 0) {
    uint2 o;
    o.x = (unsigned)f2bf(a0) | ((unsigned)f2bf(a1) << 16);
    o.y = (unsigned)f2bf(a2) | ((unsigned)f2bf(a3) << 16);
    h0b2[(long)node * 32 + li] = o;
  }
}

// K7/K8: MFMA GEMM, BM=64 tile, 4 waves (wave w = rows w*16..+15, all 128
// cols). Epilogue staged through LDS for coalesced uint4 stores.
template <bool RELU, bool BN>
__global__ __launch_bounds__(256) void k_mm(const unsigned short* __restrict__ Ab,
                                            const unsigned short* __restrict__ WtSwz,
                                            const float* __restrict__ bias,
                                            unsigned short* __restrict__ Cb,
                                            float* __restrict__ bnSum,
                                            float* __restrict__ bnSq) {
  __shared__ float sC[64 * 128];  // 32 KiB; phase1 aliases as sW (bf16 W)
  __shared__ float sbias[128];
  __shared__ float sbn[256];
  unsigned short* sW = (unsigned short*)sC;
  int tid = threadIdx.x;
#pragma unroll
  for (int i = 0; i < 8; ++i)
    ((uint4*)sW)[tid + 256 * i] = ((const uint4*)WtSwz)[tid + 256 * i];
  if (tid < 128) sbias[tid] = bias[tid];
  sbn[tid] = 0.f;
  __syncthreads();

  int w = tid >> 6, lane = tid & 63;
  int l4 = lane >> 4, l15 = lane & 15;
  int rowW = blockIdx.x * 64 + w * 16;

  int r = rowW + l15;
  if (r > NNODES - 1) r = NNODES - 1;
  bf16x8 af[4];
#pragma unroll
  for (int ks = 0; ks < 4; ++ks)
    af[ks] = *(const bf16x8*)(Ab + (long)r * 128 + ks * 32 + l4 * 8);

  f32x4 acc[8];
#pragma unroll
  for (int ni = 0; ni < 8; ++ni) acc[ni] = (f32x4){0.f, 0.f, 0.f, 0.f};

#pragma unroll
  for (int ks = 0; ks < 4; ++ks) {
#pragma unroll
    for (int ni = 0; ni < 8; ++ni) {
      int n = ni * 16 + l15;
      int k = ks * 32 + l4 * 8;
      bf16x8 bf = *(const bf16x8*)(sW + n * 128 + (k ^ ((n & 7) << 3)));
      acc[ni] = __builtin_amdgcn_mfma_f32_16x16x32_bf16(af[ks], bf, acc[ni], 0, 0, 0);
    }
  }

  __syncthreads();  // done reading sW; reuse as sC
#pragma unroll
  for (int ni = 0; ni < 8; ++ni)
#pragma unroll
    for (int rr = 0; rr < 4; ++rr)
      sC[(w * 16 + l4 * 4 + rr) * 128 + ni * 16 + l15] = acc[ni][rr];
  __syncthreads();

  // pack phase: thread handles cols colb..colb+7, rows rowl+16g.
  int colb = (tid & 15) * 8, rowl = tid >> 4;
  float ls[8], lq[8];
#pragma unroll
  for (int j = 0; j < 8; ++j) { ls[j] = 0.f; lq[j] = 0.f; }
#pragma unroll
  for (int g = 0; g < 4; ++g) {
    int row = rowl + g * 16;
    int grow = blockIdx.x * 64 + row;
    if (grow < NNODES) {
      uint4 o;
      unsigned ov[4];
#pragma unroll
      for (int p = 0; p < 4; ++p) {
        float v0 = sC[row * 128 + colb + 2 * p] + sbias[colb + 2 * p];
        float v1 = sC[row * 128 + colb + 2 * p + 1] + sbias[colb + 2 * p + 1];
        if (RELU) { v0 = fmaxf(v0, 0.f); v1 = fmaxf(v1, 0.f); }
        if (BN) {
          ls[2 * p] += v0; lq[2 * p] += v0 * v0;
          ls[2 * p + 1] += v1; lq[2 * p + 1] += v1 * v1;
        }
        ov[p] = (unsigned)f2bf(v0) | ((unsigned)f2bf(v1) << 16);
      }
      o.x = ov[0]; o.y = ov[1]; o.z = ov[2]; o.w = ov[3];
      *(uint4*)(Cb + (long)grow * 128 + colb) = o;
    }
  }
  if (BN) {
#pragma unroll
    for (int j = 0; j < 8; ++j) {
      atomicAdd(&sbn[colb + j], ls[j]);
      atomicAdd(&sbn[128 + colb + j], lq[j]);
    }
    __syncthreads();
    if (tid < 128) {
      atomicAdd(&bnSum[tid], sbn[tid]);
      atomicAdd(&bnSq[tid], sbn[128 + tid]);
    }
  }
}

// K9: fused BN-finalize + out = h2b*scale + shift + xb. 8 elems/thread.
__global__ __launch_bounds__(256) void k_epi(const uint4* __restrict__ h2b4,
                                             const uint4* __restrict__ xb4,
                                             const float* __restrict__ bnSum,
                                             const float* __restrict__ bnSq,
                                             const float* __restrict__ gamma,
                                             const float* __restrict__ beta,
                                             float4* __restrict__ out4) {
  __shared__ float ssc[128], ssh[128];
  int tid = threadIdx.x;
  if (tid < 128) {
    float m = bnSum[tid] * (1.0f / NNODES);
    float var = bnSq[tid] * (1.0f / NNODES) - m * m;
    float sc = gamma[tid] * rsqrtf(var + BN_EPS);
    ssc[tid] = sc;
    ssh[tid] = beta[tid] - m * sc;
  }
  __syncthreads();
  long j = (long)blockIdx.x * 256 + tid;  // unit of 8 elems
  int c = (int)((j * 8) & 127);
  uint4 h = h2b4[j], xr = xb4[j];
  float4 sa = *(float4*)(ssc + c), sb = *(float4*)(ssc + c + 4);
  float4 fa = *(float4*)(ssh + c), fb = *(float4*)(ssh + c + 4);
  float4 oa, ob;
  oa.x = fmaf(bfLO(h.x), sa.x, fa.x) + bfLO(xr.x);
  oa.y = fmaf(bfHI(h.x), sa.y, fa.y) + bfHI(xr.x);
  oa.z = fmaf(bfLO(h.y), sa.z, fa.z) + bfLO(xr.y);
  oa.w = fmaf(bfHI(h.y), sa.w, fa.w) + bfHI(xr.y);
  ob.x = fmaf(bfLO(h.z), sb.x, fb.x) + bfLO(xr.z);
  ob.y = fmaf(bfHI(h.z), sb.y, fb.y) + bfHI(xr.z);
  ob.z = fmaf(bfLO(h.w), sb.z, fb.z) + bfLO(xr.w);
  ob.w = fmaf(bfHI(h.w), sb.w, fb.w) + bfHI(xr.w);
  out4[2 * j] = oa;
  out4[2 * j + 1] = ob;
}

extern "C" void kernel_launch(void* const* d_in, const int* in_sizes, int n_in,
                              void* d_out, int out_size, void* d_ws, size_t ws_size,
                              hipStream_t stream) {
  const float* x     = (const float*)d_in[0];
  const int*   e32   = (const int*)d_in[1];
  const float* W1    = (const float*)d_in[2];
  const float* b1    = (const float*)d_in[3];
  const float* W2    = (const float*)d_in[4];
  const float* b2    = (const float*)d_in[5];
  const float* gamma = (const float*)d_in[6];
  const float* beta  = (const float*)d_in[7];
  float* out = (float*)d_out;

  char* ws = (char*)d_ws;
  const size_t BFB = (size_t)NNODES * DD * 2;  // 25.6 MB
  unsigned short* xb  = (unsigned short*)ws;
  unsigned short* h0b = (unsigned short*)(ws + BFB);
  unsigned short* h1b = (unsigned short*)(ws + 2 * BFB);
  unsigned short* h2b = h0b;  // GEMM2 out reuses h0b

  int* rowPtr     = (int*)(ws + 3 * BFB);           // [NNODES+4]
  int* edgeSrc    = rowPtr + NNODES + 4;            // [NEDGES]
  unsigned* stage = (unsigned*)(edgeSrc + NEDGES);  // [NEDGES]
  int* cnt        = (int*)(stage + NEDGES);         // [NBUCK*PBLK]
  int* off        = cnt + NBUCK * PBLK;             // [NBUCK*PBLK]
  int* bucketTot  = off + NBUCK * PBLK;             // [128]
  int* bucketBase = bucketTot + 128;                // [128]

  unsigned short* wt1 = (unsigned short*)(bucketBase + 128);
  unsigned short* wt2 = wt1 + 16384;
  float* bnSum = (float*)(wt2 + 16384);
  float* bnSq  = bnSum + 128;

  k_prep<<<6764, 256, 0, stream>>>(x, W1, W2, xb, wt1, wt2, bnSum, e32, cnt);
  k_lscan<<<NBUCK, 256, 0, stream>>>(cnt, off, bucketTot);
  k_bscan<<<1, 128, 0, stream>>>(bucketTot, bucketBase, rowPtr);
  k_ppart<<<PBLK, 256, 0, stream>>>(e32, off, bucketBase, stage);
  k_bucket<<<NBUCK, 256, 0, stream>>>(stage, bucketBase, bucketTot, rowPtr,
                                      edgeSrc);
  k_gather<<<25000, 256, 0, stream>>>((const uint2*)xb, rowPtr, edgeSrc,
                                      (uint2*)h0b);
  k_mm<true, false><<<1563, 256, 0, stream>>>(h0b, wt1, b1, h1b, nullptr,
                                              nullptr);
  k_mm<false, true><<<1563, 256, 0, stream>>>(h1b, wt2, b2, h2b, bnSum, bnSq);
  k_epi<<<6250, 256, 0, stream>>>((const uint4*)h2b, (const uint4*)xb, bnSum,
                                  bnSq, gamma, beta, (float4*)out);
}

// Round 7
// 210.239 us; speedup vs baseline: 13.8007x; 1.2092x over previous
//
#include <hip/hip_runtime.h>
#include <math.h>

#define NNODES 100000
#define NEDGES 1600000
#define DD 128
#define BN_EPS 1e-5f

#define NBUCK 98     // ceil(100000/1024)
#define BUCKW 1024   // dsts per bucket (bucket = dst>>10)
#define PBLK 512     // partition blocks
#define PCHUNK 3125  // edges per partition block (512*3125 = 1.6M exact)

typedef __attribute__((ext_vector_type(8))) short bf16x8;
typedef __attribute__((ext_vector_type(4))) float f32x4;

__device__ __forceinline__ unsigned short f2bf(float f) {  // RNE f32->bf16
  unsigned u = __builtin_bit_cast(unsigned, f);
  u = (u + 0x7fffu + ((u >> 16) & 1u)) >> 16;
  return (unsigned short)u;
}
__device__ __forceinline__ float bfLO(unsigned u) {
  return __builtin_bit_cast(float, u << 16);
}
__device__ __forceinline__ float bfHI(unsigned u) {
  return __builtin_bit_cast(float, u & 0xffff0000u);
}

// ---------------------------------------------------------------------------
// ws layout:
//   xb   [100000][128] bf16   25.6 MB
//   h0b  [100000][128] bf16   (agg; overwritten in-place by h2 in k_fmm)
//   h1b  region unused (kept for layout stability)
//   rowPtr[100004] | edgeSrc[1.6M] | stage[1.6M] | cnt[98*512] | off[98*512]
//   bucketTot[128] | bucketBase[128] | wt1[16384] wt2[16384] (bf16)
//   bnSum[128] bnSq[128]
// ---------------------------------------------------------------------------

// K1: fused prep. blocks 0-1: W->bf16 transposed+swizzled + zero bn.
// blocks 2..6251: x->bf16. blocks 6252..6763: per-(block,bucket) histogram.
__global__ __launch_bounds__(256) void k_prep(const float* __restrict__ x,
                                              const float* __restrict__ W1,
                                              const float* __restrict__ W2,
                                              unsigned short* __restrict__ xb,
                                              unsigned short* __restrict__ wt1,
                                              unsigned short* __restrict__ wt2,
                                              float* __restrict__ bnAcc,
                                              const int* __restrict__ e32,
                                              int* __restrict__ cnt) {
  __shared__ int sc[NBUCK];
  int bid = blockIdx.x, tid = threadIdx.x;
  if (bid < 2) {
    const float* W = bid ? W2 : W1;
    unsigned short* wt = bid ? wt2 : wt1;
    if (tid < 128) {
      int n = tid;
      for (int k = 0; k < 128; ++k)
        wt[n * 128 + (k ^ ((n & 7) << 3))] = f2bf(W[k * 128 + n]);
    } else {
      bnAcc[(bid ? 0 : 128) + (tid - 128)] = 0.f;  // bnSum / bnSq halves
    }
  } else if (bid < 6252) {  // x -> bf16 : 6250 blocks * 2048 elems
    long j = (long)(bid - 2) * 2048 + tid * 8;
    float4 a = *(const float4*)(x + j);
    float4 b = *(const float4*)(x + j + 4);
    uint4 o;
    o.x = (unsigned)f2bf(a.x) | ((unsigned)f2bf(a.y) << 16);
    o.y = (unsigned)f2bf(a.z) | ((unsigned)f2bf(a.w) << 16);
    o.z = (unsigned)f2bf(b.x) | ((unsigned)f2bf(b.y) << 16);
    o.w = (unsigned)f2bf(b.z) | ((unsigned)f2bf(b.w) << 16);
    *(uint4*)(xb + j) = o;
  } else {  // pcount
    int blk = bid - 6252;
    int z = (tid < 64) ? (e32[2 * tid + 1] == 0) : 1;
    int is64 = __syncthreads_and(z);
    for (int i = tid; i < NBUCK; i += 256) sc[i] = 0;
    __syncthreads();
    const int* dstp = is64 ? (e32 + 2 * (long)NEDGES) : (e32 + NEDGES);
    long e0 = (long)blk * PCHUNK;
    for (int i = tid; i < PCHUNK; i += 256) {
      long e = e0 + i;
      int d = is64 ? dstp[2 * e] : dstp[e];
      atomicAdd(&sc[d >> 10], 1);
    }
    __syncthreads();
    for (int i = tid; i < NBUCK; i += 256) cnt[i * PBLK + blk] = sc[i];
  }
}

// K2: per-bucket local scan of 512 block counts -> off (local), bucketTot.
__global__ __launch_bounds__(256) void k_lscan(const int* __restrict__ cnt,
                                               int* __restrict__ off,
                                               int* __restrict__ bucketTot) {
  __shared__ int s[256];
  int b = blockIdx.x, tid = threadIdx.x;
  int v0 = cnt[b * PBLK + 2 * tid], v1 = cnt[b * PBLK + 2 * tid + 1];
  s[tid] = v0 + v1;
  __syncthreads();
  for (int o = 1; o < 256; o <<= 1) {
    int v = (tid >= o) ? s[tid - o] : 0;
    __syncthreads();
    s[tid] += v;
    __syncthreads();
  }
  int excl = s[tid] - v0 - v1;
  off[b * PBLK + 2 * tid] = excl;
  off[b * PBLK + 2 * tid + 1] = excl + v0;
  if (tid == 255) bucketTot[b] = s[255];
}

// K3: exclusive scan of 98 bucket totals -> bucketBase; set rowPtr[N].
__global__ __launch_bounds__(128) void k_bscan(const int* __restrict__ bucketTot,
                                               int* __restrict__ bucketBase,
                                               int* __restrict__ rowPtr) {
  __shared__ int s[128];
  int tid = threadIdx.x;
  s[tid] = (tid < NBUCK) ? bucketTot[tid] : 0;
  __syncthreads();
  for (int o = 1; o < 128; o <<= 1) {
    int v = (tid >= o) ? s[tid - o] : 0;
    __syncthreads();
    s[tid] += v;
    __syncthreads();
  }
  if (tid < NBUCK) bucketBase[tid] = (tid == 0) ? 0 : s[tid - 1];
  if (tid == 0) rowPtr[NNODES] = NEDGES;
}

// K4: partition edges into bucket-major stage, packed (src<<10)|dstLocal.
__global__ __launch_bounds__(256) void k_ppart(const int* __restrict__ e32,
                                               const int* __restrict__ off,
                                               const int* __restrict__ bucketBase,
                                               unsigned* __restrict__ stage) {
  __shared__ int cur[NBUCK];
  int tid = threadIdx.x, blk = blockIdx.x;
  int z = (tid < 64) ? (e32[2 * tid + 1] == 0) : 1;
  int is64 = __syncthreads_and(z);
  if (tid < NBUCK) cur[tid] = off[tid * PBLK + blk] + bucketBase[tid];
  __syncthreads();
  const int* dstp = is64 ? (e32 + 2 * (long)NEDGES) : (e32 + NEDGES);
  long e0 = (long)blk * PCHUNK;
  for (int i = tid; i < PCHUNK; i += 256) {
    long e = e0 + i;
    int d = is64 ? dstp[2 * e] : dstp[e];
    int sv = is64 ? e32[2 * e] : e32[e];
    int pos = atomicAdd(&cur[d >> 10], 1);
    stage[pos] = ((unsigned)sv << 10) | (unsigned)(d & (BUCKW - 1));
  }
}

// K5: one block per bucket: LDS histogram -> scan -> rowPtr; place edgeSrc.
__global__ __launch_bounds__(256) void k_bucket(const unsigned* __restrict__ stage,
                                                const int* __restrict__ bucketBase,
                                                const int* __restrict__ bucketTot,
                                                int* __restrict__ rowPtr,
                                                int* __restrict__ edgeSrc) {
  __shared__ int sdeg[BUCKW];
  __shared__ int srow[BUCKW];
  __shared__ int ss[256];
  int b = blockIdx.x, tid = threadIdx.x;
  int base = bucketBase[b], tot = bucketTot[b];
  for (int i = tid; i < BUCKW; i += 256) sdeg[i] = 0;
  __syncthreads();
  const unsigned* st = stage + base;
  for (int i = tid; i < tot; i += 256) atomicAdd(&sdeg[st[i] & (BUCKW - 1)], 1);
  __syncthreads();
  int j = tid * 4;
  int d0 = sdeg[j], d1 = sdeg[j + 1], d2 = sdeg[j + 2], d3 = sdeg[j + 3];
  int tsum = d0 + d1 + d2 + d3;
  ss[tid] = tsum;
  __syncthreads();
  for (int o = 1; o < 256; o <<= 1) {
    int v = (tid >= o) ? ss[tid - o] : 0;
    __syncthreads();
    ss[tid] += v;
    __syncthreads();
  }
  int excl = ss[tid] - tsum;
  srow[j] = excl;
  srow[j + 1] = excl + d0;
  srow[j + 2] = excl + d0 + d1;
  srow[j + 3] = excl + d0 + d1 + d2;
  __syncthreads();
  for (int i = tid; i < BUCKW; i += 256) {
    int dst = b * BUCKW + i;
    if (dst < NNODES) rowPtr[dst] = base + srow[i];
    sdeg[i] = srow[i];  // reuse as cursor
  }
  __syncthreads();
  for (int i = tid; i < tot; i += 256) {
    unsigned p = st[i];
    int pos = atomicAdd(&sdeg[p & (BUCKW - 1)], 1);
    edgeSrc[base + pos] = (int)(p >> 10);
  }
}

// K6: gather at 8B/lane. Wave = 1 node; lanes 0-31 edge e, lanes 32-63 e+1.
__global__ __launch_bounds__(256) void k_gather(const uint2* __restrict__ xb2,
                                                const int* __restrict__ rowPtr,
                                                const int* __restrict__ edgeSrc,
                                                uint2* __restrict__ h0b2) {
  int node = (blockIdx.x * 256 + threadIdx.x) >> 6;
  int lane = threadIdx.x & 63;
  if (node >= NNODES) return;
  int li = lane & 31, half = lane >> 5;
  int beg = rowPtr[node], end = rowPtr[node + 1];
  float a0 = 0.f, a1 = 0.f, a2 = 0.f, a3 = 0.f;
  if (half == 0) {  // init from own row
    uint2 u = xb2[(long)node * 32 + li];
    a0 = bfLO(u.x); a1 = bfHI(u.x); a2 = bfLO(u.y); a3 = bfHI(u.y);
  }
  int e = beg;
  for (; e + 4 <= end; e += 4) {
    int sA_ = edgeSrc[e + half];
    int sB_ = edgeSrc[e + 2 + half];
    uint2 va = xb2[(long)sA_ * 32 + li];
    uint2 vb = xb2[(long)sB_ * 32 + li];
    a0 += bfLO(va.x); a1 += bfHI(va.x); a2 += bfLO(va.y); a3 += bfHI(va.y);
    a0 += bfLO(vb.x); a1 += bfHI(vb.x); a2 += bfLO(vb.y); a3 += bfHI(vb.y);
  }
  if (e + 2 <= end) {
    int s_ = edgeSrc[e + half];
    uint2 v = xb2[(long)s_ * 32 + li];
    a0 += bfLO(v.x); a1 += bfHI(v.x); a2 += bfLO(v.y); a3 += bfHI(v.y);
    e += 2;
  }
  if (e < end && half == 0) {  // odd tail: lower half only
    int s_ = edgeSrc[e];
    uint2 v = xb2[(long)s_ * 32 + li];
    a0 += bfLO(v.x); a1 += bfHI(v.x); a2 += bfLO(v.y); a3 += bfHI(v.y);
  }
  a0 += __shfl_xor(a0, 32, 64);
  a1 += __shfl_xor(a1, 32, 64);
  a2 += __shfl_xor(a2, 32, 64);
  a3 += __shfl_xor(a3, 32, 64);
  if (half == 0) {
    uint2 o;
    o.x = (unsigned)f2bf(a0) | ((unsigned)f2bf(a1) << 16);
    o.y = (unsigned)f2bf(a2) | ((unsigned)f2bf(a3) << 16);
    h0b2[(long)node * 32 + li] = o;
  }
}

// K7: FUSED MLP: h2 = (relu(h0@W1+b1))@W2 + b2, written in-place over h0b,
// plus BN partial sums. 128-row block, 4 waves each 64x64 output sub-tile.
// LDS: sA = W1 (32KB) then reused as swizzled h1 tile; sW2 = W2 (32KB).
// h1 LDS swizzle: elem (row,k) at sA[row*128 + (k ^ ((row&7)<<3))] -> b128
// A-frag reads conflict-free; W reads use the k_prep swizzle (n&7).
__global__ __launch_bounds__(256) void k_fmm(const unsigned short* __restrict__ Ab,
                                             const unsigned short* __restrict__ Wt1,
                                             const unsigned short* __restrict__ Wt2,
                                             const float* __restrict__ b1,
                                             const float* __restrict__ b2,
                                             unsigned short* __restrict__ Cb,
                                             float* __restrict__ bnSum,
                                             float* __restrict__ bnSq) {
  __shared__ unsigned short sA[128 * 128];   // W1, then h1 tile
  __shared__ unsigned short sW2[128 * 128];
  __shared__ float sb1[128], sb2[128];
  __shared__ float sbn[256];
  int tid = threadIdx.x;
#pragma unroll
  for (int i = 0; i < 8; ++i) {
    ((uint4*)sA)[tid + 256 * i] = ((const uint4*)Wt1)[tid + 256 * i];
    ((uint4*)sW2)[tid + 256 * i] = ((const uint4*)Wt2)[tid + 256 * i];
  }
  if (tid < 128) { sb1[tid] = b1[tid]; sb2[tid] = b2[tid]; }
  sbn[tid] = 0.f;

  int w = tid >> 6, lane = tid & 63;
  int wr = w >> 1, wc = w & 1;
  int l4 = lane >> 4, l15 = lane & 15;
  int blkRow = blockIdx.x * 128;

  // A fragments from global (independent of LDS staging -> overlaps).
  bf16x8 af[4][4];
#pragma unroll
  for (int mi = 0; mi < 4; ++mi) {
    int r = blkRow + wr * 64 + mi * 16 + l15;
    if (r > NNODES - 1) r = NNODES - 1;  // clamp; OOB rows discarded later
#pragma unroll
    for (int ks = 0; ks < 4; ++ks)
      af[mi][ks] = *(const bf16x8*)(Ab + (long)r * 128 + ks * 32 + l4 * 8);
  }
  __syncthreads();

  // ---- GEMM1 ----
  f32x4 acc[4][4];
#pragma unroll
  for (int mi = 0; mi < 4; ++mi)
#pragma unroll
    for (int ni = 0; ni < 4; ++ni) acc[mi][ni] = (f32x4){0.f, 0.f, 0.f, 0.f};
#pragma unroll
  for (int ks = 0; ks < 4; ++ks) {
#pragma unroll
    for (int ni = 0; ni < 4; ++ni) {
      int n = wc * 64 + ni * 16 + l15;
      int k = ks * 32 + l4 * 8;
      bf16x8 bf = *(const bf16x8*)(sA + n * 128 + (k ^ ((n & 7) << 3)));
#pragma unroll
      for (int mi = 0; mi < 4; ++mi)
        acc[mi][ni] = __builtin_amdgcn_mfma_f32_16x16x32_bf16(af[mi][ks], bf,
                                                              acc[mi][ni], 0, 0, 0);
    }
  }
  __syncthreads();  // all waves done reading W1 -> reuse sA as h1 tile

  // ---- relu + bias -> bf16 h1 tile in LDS (swizzled) ----
#pragma unroll
  for (int mi = 0; mi < 4; ++mi) {
#pragma unroll
    for (int ni = 0; ni < 4; ++ni) {
      int col = wc * 64 + ni * 16 + l15;
      float bv = sb1[col];
#pragma unroll
      for (int r = 0; r < 4; ++r) {
        int row = wr * 64 + mi * 16 + l4 * 4 + r;  // local row
        float v = fmaxf(acc[mi][ni][r] + bv, 0.f);
        sA[row * 128 + (col ^ ((row & 7) << 3))] = f2bf(v);
      }
    }
  }
  __syncthreads();

  // ---- GEMM2 ----
  bf16x8 af2[4][4];
#pragma unroll
  for (int mi = 0; mi < 4; ++mi) {
    int row = wr * 64 + mi * 16 + l15;
#pragma unroll
    for (int ks = 0; ks < 4; ++ks) {
      int k = ks * 32 + l4 * 8;
      af2[mi][ks] = *(const bf16x8*)(sA + row * 128 + (k ^ ((row & 7) << 3)));
    }
  }
#pragma unroll
  for (int mi = 0; mi < 4; ++mi)
#pragma unroll
    for (int ni = 0; ni < 4; ++ni) acc[mi][ni] = (f32x4){0.f, 0.f, 0.f, 0.f};
#pragma unroll
  for (int ks = 0; ks < 4; ++ks) {
#pragma unroll
    for (int ni = 0; ni < 4; ++ni) {
      int n = wc * 64 + ni * 16 + l15;
      int k = ks * 32 + l4 * 8;
      bf16x8 bf = *(const bf16x8*)(sW2 + n * 128 + (k ^ ((n & 7) << 3)));
#pragma unroll
      for (int mi = 0; mi < 4; ++mi)
        acc[mi][ni] = __builtin_amdgcn_mfma_f32_16x16x32_bf16(af2[mi][ks], bf,
                                                              acc[mi][ni], 0, 0, 0);
    }
  }

  // ---- epilogue: h2 (bf16) + BN partials ----
#pragma unroll
  for (int ni = 0; ni < 4; ++ni) {
    int n = wc * 64 + ni * 16 + l15;
    float bv = sb2[n];
    float ls = 0.f, lq = 0.f;
#pragma unroll
    for (int mi = 0; mi < 4; ++mi) {
#pragma unroll
      for (int r = 0; r < 4; ++r) {
        int row = blkRow + wr * 64 + mi * 16 + l4 * 4 + r;
        if (row < NNODES) {
          float v = acc[mi][ni][r] + bv;
          Cb[(long)row * 128 + n] = f2bf(v);
          ls += v; lq += v * v;
        }
      }
    }
    atomicAdd(&sbn[n], ls);
    atomicAdd(&sbn[128 + n], lq);
  }
  __syncthreads();
  if (tid < 128) {
    atomicAdd(&bnSum[tid], sbn[tid]);
    atomicAdd(&bnSq[tid], sbn[128 + tid]);
  }
}

// K8: fused BN-finalize + out = h2b*scale + shift + xb. 8 elems/thread.
__global__ __launch_bounds__(256) void k_epi(const uint4* __restrict__ h2b4,
                                             const uint4* __restrict__ xb4,
                                             const float* __restrict__ bnSum,
                                             const float* __restrict__ bnSq,
                                             const float* __restrict__ gamma,
                                             const float* __restrict__ beta,
                                             float4* __restrict__ out4) {
  __shared__ float ssc[128], ssh[128];
  int tid = threadIdx.x;
  if (tid < 128) {
    float m = bnSum[tid] * (1.0f / NNODES);
    float var = bnSq[tid] * (1.0f / NNODES) - m * m;
    float sc = gamma[tid] * rsqrtf(var + BN_EPS);
    ssc[tid] = sc;
    ssh[tid] = beta[tid] - m * sc;
  }
  __syncthreads();
  long j = (long)blockIdx.x * 256 + tid;  // unit of 8 elems
  int c = (int)((j * 8) & 127);
  uint4 h = h2b4[j], xr = xb4[j];
  float4 sa = *(float4*)(ssc + c), sb = *(float4*)(ssc + c + 4);
  float4 fa = *(float4*)(ssh + c), fb = *(float4*)(ssh + c + 4);
  float4 oa, ob;
  oa.x = fmaf(bfLO(h.x), sa.x, fa.x) + bfLO(xr.x);
  oa.y = fmaf(bfHI(h.x), sa.y, fa.y) + bfHI(xr.x);
  oa.z = fmaf(bfLO(h.y), sa.z, fa.z) + bfLO(xr.y);
  oa.w = fmaf(bfHI(h.y), sa.w, fa.w) + bfHI(xr.y);
  ob.x = fmaf(bfLO(h.z), sb.x, fb.x) + bfLO(xr.z);
  ob.y = fmaf(bfHI(h.z), sb.y, fb.y) + bfHI(xr.z);
  ob.z = fmaf(bfLO(h.w), sb.z, fb.z) + bfLO(xr.w);
  ob.w = fmaf(bfHI(h.w), sb.w, fb.w) + bfHI(xr.w);
  out4[2 * j] = oa;
  out4[2 * j + 1] = ob;
}

extern "C" void kernel_launch(void* const* d_in, const int* in_sizes, int n_in,
                              void* d_out, int out_size, void* d_ws, size_t ws_size,
                              hipStream_t stream) {
  const float* x     = (const float*)d_in[0];
  const int*   e32   = (const int*)d_in[1];
  const float* W1    = (const float*)d_in[2];
  const float* b1    = (const float*)d_in[3];
  const float* W2    = (const float*)d_in[4];
  const float* b2    = (const float*)d_in[5];
  const float* gamma = (const float*)d_in[6];
  const float* beta  = (const float*)d_in[7];
  float* out = (float*)d_out;

  char* ws = (char*)d_ws;
  const size_t BFB = (size_t)NNODES * DD * 2;  // 25.6 MB
  unsigned short* xb  = (unsigned short*)ws;
  unsigned short* h0b = (unsigned short*)(ws + BFB);
  unsigned short* h2b = h0b;  // fused kernel writes h2 in-place over h0b

  int* rowPtr     = (int*)(ws + 3 * BFB);           // [NNODES+4]
  int* edgeSrc    = rowPtr + NNODES + 4;            // [NEDGES]
  unsigned* stage = (unsigned*)(edgeSrc + NEDGES);  // [NEDGES]
  int* cnt        = (int*)(stage + NEDGES);         // [NBUCK*PBLK]
  int* off        = cnt + NBUCK * PBLK;             // [NBUCK*PBLK]
  int* bucketTot  = off + NBUCK * PBLK;             // [128]
  int* bucketBase = bucketTot + 128;                // [128]

  unsigned short* wt1 = (unsigned short*)(bucketBase + 128);
  unsigned short* wt2 = wt1 + 16384;
  float* bnSum = (float*)(wt2 + 16384);
  float* bnSq  = bnSum + 128;

  k_prep<<<6764, 256, 0, stream>>>(x, W1, W2, xb, wt1, wt2, bnSum, e32, cnt);
  k_lscan<<<NBUCK, 256, 0, stream>>>(cnt, off, bucketTot);
  k_bscan<<<1, 128, 0, stream>>>(bucketTot, bucketBase, rowPtr);
  k_ppart<<<PBLK, 256, 0, stream>>>(e32, off, bucketBase, stage);
  k_bucket<<<NBUCK, 256, 0, stream>>>(stage, bucketBase, bucketTot, rowPtr,
                                      edgeSrc);
  k_gather<<<25000, 256, 0, stream>>>((const uint2*)xb, rowPtr, edgeSrc,
                                      (uint2*)h0b);
  k_fmm<<<782, 256, 0, stream>>>(h0b, wt1, wt2, b1, b2, h2b, bnSum, bnSq);
  k_epi<<<6250, 256, 0, stream>>>((const uint4*)h2b, (const uint4*)xb, bnSum,
                                  bnSq, gamma, beta, (float4*)out);
}